// Round 9
// baseline (396.946 us; speedup 1.0000x reference)
//
#include <hip/hip_runtime.h>
#include <hip/hip_bf16.h>

#define N_NODES 20000
#define N_EDGES 320000
#define TOT_E   (N_EDGES + N_NODES)   // 340000 with self loops
#define IN_CH   128
#define HEADS   8
#define CH      33
#define DD      264                   // HEADS*CH
#define OUTW    132
#define NEG     0.2f

#define LDB     272                   // bf16 payload row stride (34 uint4 slots)
#define LDA     320                   // hA bf16 row stride, K padded to 10*32
#define NT_HID  18                    // 17 payload tiles + 1 stats tile [was|wad]
#define NT_HEAD 12                    // head gemm tiles (132 -> 192, zero-padded)
#define PK0     4
#define PKH     10
#define PKO     10

typedef unsigned short ushort;
typedef unsigned int uint32;
typedef short bf16x8 __attribute__((ext_vector_type(8)));
typedef float f32x4  __attribute__((ext_vector_type(4)));

__device__ inline void split2(float v, ushort& hi, ushort& lo) {
    __hip_bfloat16 h = __float2bfloat16(v);
    float r = v - __bfloat162float(h);
    __hip_bfloat16 l = __float2bfloat16(r);
    hi = *(ushort*)&h;
    lo = *(ushort*)&l;
}

__device__ inline float bf2f(ushort u) {
    union { unsigned int i; float f; } c;
    c.i = ((unsigned int)u) << 16;
    return c.f;
}

// low ushort of dword -> f32 (shift), high ushort -> f32 (free AND)
__device__ inline float bflo(uint32 d) {
    union { unsigned int i; float f; } c;
    c.i = d << 16;
    return c.f;
}
__device__ inline float bfhi(uint32 d) {
    union { unsigned int i; float f; } c;
    c.i = d & 0xffff0000u;
    return c.f;
}

// async global->LDS, 16B per lane; LDS dst is wave-uniform base + lane*16
__device__ __forceinline__ void ld_lds16(const ushort* g, ushort* l) {
    __builtin_amdgcn_global_load_lds(
        (const __attribute__((address_space(1))) void*)g,
        (__attribute__((address_space(3))) void*)l, 16, 0, 0);
}

// ---------------- CSR build ----------------

__global__ void deg_k(const int* __restrict__ ei, int* __restrict__ deg) {
    int e = blockIdx.x * 256 + threadIdx.x;
    if (e >= TOT_E) return;
    int dst = (e < N_EDGES) ? ei[N_EDGES + e] : (e - N_EDGES);
    atomicAdd(&deg[dst], 1);
}

__global__ __launch_bounds__(1024) void scan_k(const int* __restrict__ deg,
                                               int* __restrict__ rowp) {
    __shared__ int part[1024];
    const int PER = 20;
    int t = threadIdx.x;
    int base = t * PER;
    int s = 0;
    for (int i = 0; i < PER; ++i) {
        int idx = base + i;
        if (idx < N_NODES) s += deg[idx];
    }
    part[t] = s;
    __syncthreads();
    for (int off = 1; off < 1024; off <<= 1) {
        int v = 0;
        if (t >= off) v = part[t - off];
        __syncthreads();
        part[t] += v;
        __syncthreads();
    }
    int run = part[t] - s;
    for (int i = 0; i < PER; ++i) {
        int idx = base + i;
        if (idx < N_NODES) { rowp[idx] = run; run += deg[idx]; }
    }
    if (t == 1023) rowp[N_NODES] = part[1023];
}

__global__ void fill_k(const int* __restrict__ ei, const int* __restrict__ rowp,
                       int* __restrict__ cur, int* __restrict__ csr) {
    int e = blockIdx.x * 256 + threadIdx.x;
    if (e >= TOT_E) return;
    int src, dst;
    if (e < N_EDGES) { src = ei[e]; dst = ei[N_EDGES + e]; }
    else             { src = dst = e - N_EDGES; }
    int p = atomicAdd(&cur[dst], 1);
    csr[rowp[dst] + p] = src;
}

// ---------------- input x -> bf16 (into hAhi, stride LDA) ----------------

__global__ void splitx_k(const float* __restrict__ x, ushort* __restrict__ ahi) {
    int idx = blockIdx.x * 256 + threadIdx.x;
    if (idx >= N_NODES * IN_CH) return;
    int n = idx >> 7, k = idx & 127;
    __hip_bfloat16 h = __float2bfloat16(x[idx]);
    ahi[(size_t)n * LDA + k] = *(ushort*)&h;
}

// ---------------- all weights -> fragment-ordered hi/lo bf16, one launch ----------------

__device__ void convw_one(const float* W, const float* a_s, const float* a_d,
                          int K, int NC, int NT, ushort* fhi, ushort* flo, int gid) {
    int p = gid / (NT * 64);
    int rem = gid % (NT * 64);
    int t = rem >> 6, c = rem & 63;
    int kq = c >> 4, m = c & 15;
    int n = t * 16 + m;
    bool stats = (a_s != nullptr) && (t == NT - 1);
    ushort hi8[8], lo8[8];
#pragma unroll
    for (int j = 0; j < 8; ++j) {
        int k = p * 32 + kq * 8 + j;
        float v = 0.f;
        if (k < K) {
            if (stats) {
                const float* av = (m < 8) ? a_s : a_d;
                int h = (m < 8) ? m : m - 8;
                const float* wr = W + (size_t)k * NC + h * CH;
                float s = 0.f;
                for (int cc = 0; cc < CH; ++cc) s += wr[cc] * av[h * CH + cc];
                v = s;
            } else if (n < NC) {
                v = W[(size_t)k * NC + n];
            }
        }
        split2(v, hi8[j], lo8[j]);
    }
    size_t o = ((size_t)gid) * 8;
#pragma unroll
    for (int j = 0; j < 8; ++j) { fhi[o + j] = hi8[j]; flo[o + j] = lo8[j]; }
}

#define SEG0 (PK0 * NT_HID * 64)
#define SEGH (PKH * NT_HID * 64)
#define SEGO (PKO * NT_HEAD * 64)

__global__ void convall_k(
    const float* W0, const float* W1, const float* W2, const float* W3, const float* Wh,
    const float* as0, const float* as1, const float* as2, const float* as3,
    const float* ad0, const float* ad1, const float* ad2, const float* ad3,
    ushort* f0h, ushort* f0l, ushort* f1h, ushort* f1l, ushort* f2h, ushort* f2l,
    ushort* f3h, ushort* f3l, ushort* fhh, ushort* fhl) {
    int gid = blockIdx.x * 256 + threadIdx.x;
    if (gid < SEG0) { convw_one(W0, as0, ad0, IN_CH, DD, NT_HID, f0h, f0l, gid); return; }
    gid -= SEG0;
    if (gid < SEGH) { convw_one(W1, as1, ad1, DD, DD, NT_HID, f1h, f1l, gid); return; }
    gid -= SEGH;
    if (gid < SEGH) { convw_one(W2, as2, ad2, DD, DD, NT_HID, f2h, f2l, gid); return; }
    gid -= SEGH;
    if (gid < SEGH) { convw_one(W3, as3, ad3, DD, DD, NT_HID, f3h, f3l, gid); return; }
    gid -= SEGH;
    if (gid < SEGO) { convw_one(Wh, nullptr, nullptr, DD, OUTW, NT_HEAD, fhh, fhl, gid); }
}

// ---------------- MFMA GEMM, M=128, BK=64, swizzled A LDS ---------
// R19: global_load_lds width=16 staging; 1D y-adjacent grid.
// R20 (rerun after infra failure): TG=3 (was 6) -> 2x blocks (942 hidden /
// 628 head, ~3.7/2.5 per CU) so co-resident blocks' MFMA phases cover each
// other's staging drains. Same M-tile, staging code, LDS layout; A-stripe
// refetched 6x (trivial at 27% BW).

template<bool USE3, int TG>
__global__ __launch_bounds__(256) void gemm4_k(
    const ushort* __restrict__ Ahi, const ushort* __restrict__ Alo, int kpairs,
    const ushort* __restrict__ Bhi, const ushort* __restrict__ Blo, int NTtot, int statsY,
    ushort* __restrict__ Cb16, float* __restrict__ as_, float* __restrict__ ad_,
    float* __restrict__ C, int ldc, int ncguard, const float* __restrict__ bias) {
    extern __shared__ ushort smem[];
    ushort* AlH = smem;                       // [2][8][512] = 8192 ushorts
    ushort* BlH = smem + 8192;                // [2][TG][512]
    ushort* EXT = smem + 8192 + 2 * TG * 512;
    ushort* AlL = EXT;                        // USE3
    ushort* BlL = EXT + 8192;                 // USE3
    ushort* BstL = EXT;                       // !USE3: stats-tile lo [2][512]

    int tid = threadIdx.x;
    int ngy = NTtot / TG;
    int m0 = (blockIdx.x / ngy) * 128;
    int by = blockIdx.x % ngy;
    int t0 = by * TG;
    bool sg = (by == statsY);

    f32x4 acc[2][TG];
#pragma unroll
    for (int mt = 0; mt < 2; ++mt)
#pragma unroll
        for (int t = 0; t < TG; ++t) acc[mt][t] = (f32x4){0.f, 0.f, 0.f, 0.f};

    int w = tid >> 6, lane = tid & 63;
    int csA = (lane ^ ((lane >> 4) << 1)) * 8;

    // A-stage source mapping for this lane (slot = lane of each LDS row)
    int kqA = lane >> 4;
    int m15 = (lane ^ (kqA << 1)) & 15;

    for (int pp = 0; pp < kpairs; ++pp) {
        // ---- A tiles: 16 rows hi (+16 lo if USE3), one gload_lds per row ----
        int nArows = USE3 ? 32 : 16;
        for (int r = w; r < nArows; r += 4) {
            int hl = r >> 4;
            int panel = (r >> 3) & 1;
            int mrow16 = r & 7;
            int gm = m0 + mrow16 * 16 + m15;
            if (gm > N_NODES - 1) gm = N_NODES - 1;
            const ushort* g = (hl ? Alo : Ahi) + (size_t)gm * LDA + pp * 64 + panel * 32 + kqA * 8;
            ushort* l = (hl ? AlL : AlH) + (panel * 8 + mrow16) * 512;
            ld_lds16(g, l);
        }
        // ---- B tiles: 2*TG rows, linear ----
        for (int r = w; r < 2 * TG; r += 4) {
            int panel = r / TG, t = r % TG;
            size_t row = (size_t)((pp * 2 + panel) * NTtot + t0 + t) * 512;
            ld_lds16(Bhi + row + lane * 8, &BlH[r * 512]);
            if (USE3) ld_lds16(Blo + row + lane * 8, &BlL[r * 512]);
        }
        if (!USE3 && sg && w < 2) {
            int panel = w;
            size_t row = (size_t)((pp * 2 + panel) * NTtot + t0 + TG - 1) * 512;
            ld_lds16(Blo + row + lane * 8, &BstL[panel * 512]);
        }
        __syncthreads();

#pragma unroll
        for (int panel = 0; panel < 2; ++panel) {
            bf16x8 a0 = *(const bf16x8*)&AlH[panel * 4096 + (2 * w) * 512 + csA];
            bf16x8 a1 = *(const bf16x8*)&AlH[panel * 4096 + (2 * w + 1) * 512 + csA];
            bf16x8 l0, l1;
            if (USE3) {
                l0 = *(const bf16x8*)&AlL[panel * 4096 + (2 * w) * 512 + csA];
                l1 = *(const bf16x8*)&AlL[panel * 4096 + (2 * w + 1) * 512 + csA];
            }
#pragma unroll
            for (int t = 0; t < TG; ++t) {
                bf16x8 bh = *(const bf16x8*)&BlH[(panel * TG + t) * 512 + lane * 8];
                acc[0][t] = __builtin_amdgcn_mfma_f32_16x16x32_bf16(a0, bh, acc[0][t], 0, 0, 0);
                acc[1][t] = __builtin_amdgcn_mfma_f32_16x16x32_bf16(a1, bh, acc[1][t], 0, 0, 0);
                if (USE3) {
                    bf16x8 bl = *(const bf16x8*)&BlL[(panel * TG + t) * 512 + lane * 8];
                    acc[0][t] = __builtin_amdgcn_mfma_f32_16x16x32_bf16(a0, bl, acc[0][t], 0, 0, 0);
                    acc[1][t] = __builtin_amdgcn_mfma_f32_16x16x32_bf16(a1, bl, acc[1][t], 0, 0, 0);
                    acc[0][t] = __builtin_amdgcn_mfma_f32_16x16x32_bf16(l0, bh, acc[0][t], 0, 0, 0);
                    acc[1][t] = __builtin_amdgcn_mfma_f32_16x16x32_bf16(l1, bh, acc[1][t], 0, 0, 0);
                } else if (t == TG - 1 && sg) {
                    bf16x8 bst = *(const bf16x8*)&BstL[panel * 512 + lane * 8];
                    acc[0][t] = __builtin_amdgcn_mfma_f32_16x16x32_bf16(a0, bst, acc[0][t], 0, 0, 0);
                    acc[1][t] = __builtin_amdgcn_mfma_f32_16x16x32_bf16(a1, bst, acc[1][t], 0, 0, 0);
                }
            }
        }
        __syncthreads();
    }

    int col = lane & 15;
#pragma unroll
    for (int mt = 0; mt < 2; ++mt) {
        int rbase = m0 + (2 * w + mt) * 16 + ((lane >> 4) << 2);
#pragma unroll
        for (int t = 0; t < TG; ++t) {
            int tg = t0 + t;
#pragma unroll
            for (int r = 0; r < 4; ++r) {
                int gm = rbase + r;
                if (gm >= N_NODES) continue;
                float v = acc[mt][t][r];
                if (C) {
                    int gn = tg * 16 + col;
                    if (gn < ncguard) C[(size_t)gm * ldc + gn] = v + bias[gn];
                } else if (tg < 17) {
                    __hip_bfloat16 bv = __float2bfloat16(v);
                    Cb16[(size_t)gm * LDB + tg * 16 + col] = *(ushort*)&bv;
                } else {
                    if (col < 8) as_[(size_t)gm * 8 + col] = v;
                    else         ad_[(size_t)gm * 8 + col - 8] = v;
                }
            }
        }
    }
}

// ---------------- fused softmax + gather-aggregate: 2 nodes / wave (R18) ----------

__global__ __launch_bounds__(64) void gat_k(
    const ushort* __restrict__ xb, const float* __restrict__ as_,
    const float* __restrict__ ad_, const int* __restrict__ rowp,
    const int* __restrict__ csr, const float* __restrict__ bias,
    ushort* __restrict__ outhi, ushort* __restrict__ outlo) {
    int lane = threadIdx.x;
    int half = lane >> 5, l32 = lane & 31;
    int node = blockIdx.x * 2 + half;       // grid is exactly N/2
    int r0 = rowp[node], dg = rowp[node + 1] - r0;

    __shared__ float lex[2][32][9];
    __shared__ int   lsrc[2][32];

    float ad[8];
#pragma unroll
    for (int h = 0; h < 8; ++h) ad[h] = ad_[node * 8 + h];

    // this lane's 8 channels: cb..cb+7; they span at most 2 heads
    int cb = l32 * 8;
    int ha = cb / 33;
    int hb = (cb + 7) / 33;
    bool mm[8];
#pragma unroll
    for (int j = 0; j < 8; ++j) mm[j] = ((cb + j) / 33) != ha;

    float a0[8];
#pragma unroll
    for (int j = 0; j < 8; ++j) a0[j] = 0.f;
    float a1[4] = {0.f, 0.f, 0.f, 0.f};   // tail: even l32 ch 256-259, odd 260-263
    float sm[8] = {0.f, 0.f, 0.f, 0.f, 0.f, 0.f, 0.f, 0.f};

    int mych = (dg + 31) >> 5;
    int och = __shfl_xor(mych, 32, 64);
    int maxch = mych > och ? mych : och;

    for (int c = 0; c < maxch; ++c) {
        int base = c << 5, j = base + l32;
        int s = node;
        float p8[8];
#pragma unroll
        for (int h = 0; h < 8; ++h) p8[h] = 0.f;
        if (j < dg) {
            s = csr[r0 + j];
            const float* ap = as_ + (size_t)s * 8;
#pragma unroll
            for (int h = 0; h < 8; ++h) {
                float e = ap[h] + ad[h];
                e = e > 0.f ? e : NEG * e;
                float p = __expf(e);
                p8[h] = p;
                sm[h] += p;
            }
        }
        lsrc[half][l32] = s * LDB;   // pre-scaled row offset (ushorts)
#pragma unroll
        for (int h = 0; h < 8; ++h) lex[half][l32][h] = p8[h];
        __builtin_amdgcn_wave_barrier();

        int rem = dg - base;
        int cnt = rem < 0 ? 0 : (rem > 32 ? 32 : rem);
        int cnt4 = (cnt + 3) & ~3;
        for (int jj = 0; jj < cnt4; jj += 4) {
            int o0 = lsrc[half][jj + 0], o1 = lsrc[half][jj + 1];
            int o2 = lsrc[half][jj + 2], o3 = lsrc[half][jj + 3];
            const uint4* p0 = (const uint4*)(xb + (size_t)(unsigned)o0);
            const uint4* p1 = (const uint4*)(xb + (size_t)(unsigned)o1);
            const uint4* p2 = (const uint4*)(xb + (size_t)(unsigned)o2);
            const uint4* p3 = (const uint4*)(xb + (size_t)(unsigned)o3);
            uint4 v0 = p0[l32], v1 = p1[l32], v2 = p2[l32], v3 = p3[l32];
            // tail: uint2 slots 64/65 (ch 256-263), parity-split broadcast
            const uint2* q0 = (const uint2*)p0;
            const uint2* q1 = (const uint2*)p1;
            const uint2* q2 = (const uint2*)p2;
            const uint2* q3 = (const uint2*)p3;
            uint2 t0 = q0[64 + (l32 & 1)], t1 = q1[64 + (l32 & 1)];
            uint2 t2 = q2[64 + (l32 & 1)], t3 = q3[64 + (l32 & 1)];
#pragma unroll
            for (int e = 0; e < 4; ++e) {
                const float* xr = lex[half][jj + e];
                float xa = xr[ha], xbv = xr[hb], x7 = xr[7];
                uint4 v = (e == 0) ? v0 : (e == 1) ? v1 : (e == 2) ? v2 : v3;
                uint2 t = (e == 0) ? t0 : (e == 1) ? t1 : (e == 2) ? t2 : t3;
                a0[0] += (mm[0] ? xbv : xa) * bflo(v.x);
                a0[1] += (mm[1] ? xbv : xa) * bfhi(v.x);
                a0[2] += (mm[2] ? xbv : xa) * bflo(v.y);
                a0[3] += (mm[3] ? xbv : xa) * bfhi(v.y);
                a0[4] += (mm[4] ? xbv : xa) * bflo(v.z);
                a0[5] += (mm[5] ? xbv : xa) * bfhi(v.z);
                a0[6] += (mm[6] ? xbv : xa) * bflo(v.w);
                a0[7] += (mm[7] ? xbv : xa) * bfhi(v.w);
                a1[0] += x7 * bflo(t.x);
                a1[1] += x7 * bfhi(t.x);
                a1[2] += x7 * bflo(t.y);
                a1[3] += x7 * bfhi(t.y);
            }
        }
        __builtin_amdgcn_wave_barrier();
    }

    // deferred sum reduction -> iv[8]; xor offsets <=16 stay within each half
    float iv[8];
#pragma unroll
    for (int h = 0; h < 8; ++h) {
        float s = sm[h];
        for (int off = 16; off; off >>= 1) s += __shfl_xor(s, off, 64);
        iv[h] = 1.0f / (s + 1e-16f);
    }

    // epilogue: normalize, bias + elu, bf16 out (hi; lo when requested)
    {
        float iva = iv[ha], ivb = iv[hb];
        ushort hi8[8], lo8[8];
        float4 b0 = *(const float4*)(bias + cb);
        float4 b1 = *(const float4*)(bias + cb + 4);
        float bv4[8] = {b0.x, b0.y, b0.z, b0.w, b1.x, b1.y, b1.z, b1.w};
#pragma unroll
        for (int j = 0; j < 8; ++j) {
            float v = a0[j] * (mm[j] ? ivb : iva) + bv4[j];
            v = v > 0.f ? v : (__expf(v) - 1.f);
            split2(v, hi8[j], lo8[j]);
        }
        size_t o = (size_t)node * LDA + cb;
        *(ushort4*)(outhi + o) = *(ushort4*)&hi8[0];
        *(ushort4*)(outhi + o + 4) = *(ushort4*)&hi8[4];
        if (outlo) {
            *(ushort4*)(outlo + o) = *(ushort4*)&lo8[0];
            *(ushort4*)(outlo + o + 4) = *(ushort4*)&lo8[4];
        }
    }
    if (l32 < 2) {
        ushort hi4[4], lo4[4];
        float4 bt = *(const float4*)(bias + 256 + l32 * 4);
        float bv4[4] = {bt.x, bt.y, bt.z, bt.w};
#pragma unroll
        for (int j = 0; j < 4; ++j) {
            float v = a1[j] * iv[7] + bv4[j];
            v = v > 0.f ? v : (__expf(v) - 1.f);
            split2(v, hi4[j], lo4[j]);
        }
        size_t o = (size_t)node * LDA + 256 + l32 * 4;
        *(ushort4*)(outhi + o) = *(ushort4*)hi4;
        if (outlo) *(ushort4*)(outlo + o) = *(ushort4*)lo4;
    } else if (l32 < 9) {
        ushort4 z = {0, 0, 0, 0};
        size_t o = (size_t)node * LDA + 264 + (l32 - 2) * 8;
        *(ushort4*)(outhi + o) = z;
        *(ushort4*)(outhi + o + 4) = z;
        if (outlo) {
            *(ushort4*)(outlo + o) = z;
            *(ushort4*)(outlo + o + 4) = z;
        }
    }
}

// ---------------- launch ----------------

extern "C" void kernel_launch(void* const* d_in, const int* in_sizes, int n_in,
                              void* d_out, int out_size, void* d_ws, size_t ws_size,
                              hipStream_t stream) {
    const float* x  = (const float*)d_in[0];
    const int*   ei = (const int*)d_in[1];
    const float* W[4]  = {(const float*)d_in[2],  (const float*)d_in[6],
                          (const float*)d_in[10], (const float*)d_in[14]};
    const float* As[4] = {(const float*)d_in[3],  (const float*)d_in[7],
                          (const float*)d_in[11], (const float*)d_in[15]};
    const float* Ad[4] = {(const float*)d_in[4],  (const float*)d_in[8],
                          (const float*)d_in[12], (const float*)d_in[16]};
    const float* Bb[4] = {(const float*)d_in[5],  (const float*)d_in[9],
                          (const float*)d_in[13], (const float*)d_in[17]};
    const float* Wh = (const float*)d_in[18];
    const float* bh = (const float*)d_in[19];

    // ---- workspace carve ----
    char* p = (char*)d_ws;
    ushort* hBb  = (ushort*)p;          p += (size_t)N_NODES * LDB * 2;
    ushort* hAhi = (ushort*)p;          p += (size_t)N_NODES * LDA * 2;
    ushort* hAlo = (ushort*)p;          p += (size_t)N_NODES * LDA * 2;
    float* as_  = (float*)p;            p += (size_t)N_NODES * HEADS * 4;
    float* ad_  = (float*)p;            p += (size_t)N_NODES * HEADS * 4;
    const int wsz0 = PK0 * NT_HID * 512;
    const int wszH = PKH * NT_HID * 512;
    const int wszO = PKO * NT_HEAD * 512;
    ushort* wfhi[4]; ushort* wflo[4];
    for (int l = 0; l < 4; ++l) {
        int sz = (l == 0) ? wsz0 : wszH;
        wfhi[l] = (ushort*)p; p += (size_t)sz * 2;
        wflo[l] = (ushort*)p; p += (size_t)sz * 2;
    }
    ushort* whhi = (ushort*)p; p += (size_t)wszO * 2;
    ushort* whlo = (ushort*)p; p += (size_t)wszO * 2;
    int* deg  = (int*)p;  p += N_NODES * 4;
    int* cur  = (int*)p;  p += N_NODES * 4;
    int* rowp = (int*)p;  p += (N_NODES + 1) * 4;
    int* csr  = (int*)p;  p += (size_t)TOT_E * 4;

    // ---- CSR build ----
    hipMemsetAsync(deg, 0, sizeof(int) * 2 * N_NODES, stream);  // deg + cur
    int egrid = (TOT_E + 255) / 256;
    deg_k<<<egrid, 256, 0, stream>>>(ei, deg);
    scan_k<<<1, 1024, 0, stream>>>(deg, rowp);
    fill_k<<<egrid, 256, 0, stream>>>(ei, rowp, cur, csr);

    // ---- weight + input conversion (single launch for all weights) ----
    splitx_k<<<(N_NODES * IN_CH + 255) / 256, 256, 0, stream>>>(x, hAhi);
    {
        int tot = SEG0 + 3 * SEGH + SEGO;
        convall_k<<<(tot + 255) / 256, 256, 0, stream>>>(
            W[0], W[1], W[2], W[3], Wh,
            As[0], As[1], As[2], As[3],
            Ad[0], Ad[1], Ad[2], Ad[3],
            wfhi[0], wflo[0], wfhi[1], wflo[1], wfhi[2], wflo[2],
            wfhi[3], wflo[3], whhi, whlo);
    }

    int nmb = (N_NODES + 127) / 128;              // 157
    int gG = nmb * (NT_HID / 3);                  // 157*6 = 942, y-adjacent
    int gO = nmb * (NT_HEAD / 3);                 // 157*4 = 628
    size_t smHid = (size_t)(8192 + 2 * 3 * 512 + 2 * 512) * 2;             // 24576 B
    size_t smHead = (size_t)(8192 + 2 * 3 * 512 + 8192 + 2 * 3 * 512) * 2; // 45056 B

    for (int l = 0; l < 4; ++l) {
        int kpairs = (l == 0) ? PK0 / 2 : PKH / 2;
        gemm4_k<false, 3><<<gG, 256, smHid, stream>>>(hAhi, nullptr, kpairs,
                                                      wfhi[l], wflo[l], NT_HID, 5,
                                                      hBb, as_, ad_, nullptr, 0, 0, nullptr);
        gat_k<<<N_NODES / 2, 64, 0, stream>>>(hBb, as_, ad_, rowp, csr, Bb[l],
                                              hAhi, (l == 3) ? hAlo : nullptr);
    }

    // head readout (3-term) -> fp32 out [N, 132]
    gemm4_k<true, 3><<<gO, 256, smHead, stream>>>(hAhi, hAlo, PKO / 2,
                                                  whhi, whlo, NT_HEAD, -1,
                                                  nullptr, nullptr, nullptr,
                                                  (float*)d_out, OUTW, OUTW, bh);
}

// Round 10
// 381.259 us; speedup vs baseline: 1.0411x; 1.0411x over previous
//
#include <hip/hip_runtime.h>
#include <hip/hip_bf16.h>

#define N_NODES 20000
#define N_EDGES 320000
#define TOT_E   (N_EDGES + N_NODES)   // 340000 with self loops
#define IN_CH   128
#define HEADS   8
#define CH      33
#define DD      264                   // HEADS*CH
#define OUTW    132
#define NEG     0.2f

#define LDB     272                   // bf16 payload row stride (34 uint4 slots)
#define LDA     320                   // hA bf16 row stride, K padded to 10*32
#define NT_HID  18                    // 17 payload tiles + 1 stats tile [was|wad]
#define NT_HEAD 12                    // head gemm tiles (132 -> 192, zero-padded)
#define PK0     4
#define PKH     10
#define PKO     10

typedef unsigned short ushort;
typedef unsigned int uint32;
typedef short bf16x8 __attribute__((ext_vector_type(8)));
typedef float f32x4  __attribute__((ext_vector_type(4)));

__device__ inline void split2(float v, ushort& hi, ushort& lo) {
    __hip_bfloat16 h = __float2bfloat16(v);
    float r = v - __bfloat162float(h);
    __hip_bfloat16 l = __float2bfloat16(r);
    hi = *(ushort*)&h;
    lo = *(ushort*)&l;
}

__device__ inline float bf2f(ushort u) {
    union { unsigned int i; float f; } c;
    c.i = ((unsigned int)u) << 16;
    return c.f;
}

// low ushort of dword -> f32 (shift), high ushort -> f32 (free AND)
__device__ inline float bflo(uint32 d) {
    union { unsigned int i; float f; } c;
    c.i = d << 16;
    return c.f;
}
__device__ inline float bfhi(uint32 d) {
    union { unsigned int i; float f; } c;
    c.i = d & 0xffff0000u;
    return c.f;
}

// async global->LDS, 16B per lane; LDS dst is wave-uniform base + lane*16
__device__ __forceinline__ void ld_lds16(const ushort* g, ushort* l) {
    __builtin_amdgcn_global_load_lds(
        (const __attribute__((address_space(1))) void*)g,
        (__attribute__((address_space(3))) void*)l, 16, 0, 0);
}

// ---------------- CSR build ----------------

__global__ void deg_k(const int* __restrict__ ei, int* __restrict__ deg) {
    int e = blockIdx.x * 256 + threadIdx.x;
    if (e >= TOT_E) return;
    int dst = (e < N_EDGES) ? ei[N_EDGES + e] : (e - N_EDGES);
    atomicAdd(&deg[dst], 1);
}

__global__ __launch_bounds__(1024) void scan_k(const int* __restrict__ deg,
                                               int* __restrict__ rowp) {
    __shared__ int part[1024];
    const int PER = 20;
    int t = threadIdx.x;
    int base = t * PER;
    int s = 0;
    for (int i = 0; i < PER; ++i) {
        int idx = base + i;
        if (idx < N_NODES) s += deg[idx];
    }
    part[t] = s;
    __syncthreads();
    for (int off = 1; off < 1024; off <<= 1) {
        int v = 0;
        if (t >= off) v = part[t - off];
        __syncthreads();
        part[t] += v;
        __syncthreads();
    }
    int run = part[t] - s;
    for (int i = 0; i < PER; ++i) {
        int idx = base + i;
        if (idx < N_NODES) { rowp[idx] = run; run += deg[idx]; }
    }
    if (t == 1023) rowp[N_NODES] = part[1023];
}

__global__ void fill_k(const int* __restrict__ ei, const int* __restrict__ rowp,
                       int* __restrict__ cur, int* __restrict__ csr) {
    int e = blockIdx.x * 256 + threadIdx.x;
    if (e >= TOT_E) return;
    int src, dst;
    if (e < N_EDGES) { src = ei[e]; dst = ei[N_EDGES + e]; }
    else             { src = dst = e - N_EDGES; }
    int p = atomicAdd(&cur[dst], 1);
    csr[rowp[dst] + p] = src;
}

// ---------------- input x -> bf16 (into hAhi, stride LDA) ----------------

__global__ void splitx_k(const float* __restrict__ x, ushort* __restrict__ ahi) {
    int idx = blockIdx.x * 256 + threadIdx.x;
    if (idx >= N_NODES * IN_CH) return;
    int n = idx >> 7, k = idx & 127;
    __hip_bfloat16 h = __float2bfloat16(x[idx]);
    ahi[(size_t)n * LDA + k] = *(ushort*)&h;
}

// ---------------- all weights -> fragment-ordered hi/lo bf16, one launch ----------------

__device__ void convw_one(const float* W, const float* a_s, const float* a_d,
                          int K, int NC, int NT, ushort* fhi, ushort* flo, int gid) {
    int p = gid / (NT * 64);
    int rem = gid % (NT * 64);
    int t = rem >> 6, c = rem & 63;
    int kq = c >> 4, m = c & 15;
    int n = t * 16 + m;
    bool stats = (a_s != nullptr) && (t == NT - 1);
    ushort hi8[8], lo8[8];
#pragma unroll
    for (int j = 0; j < 8; ++j) {
        int k = p * 32 + kq * 8 + j;
        float v = 0.f;
        if (k < K) {
            if (stats) {
                const float* av = (m < 8) ? a_s : a_d;
                int h = (m < 8) ? m : m - 8;
                const float* wr = W + (size_t)k * NC + h * CH;
                float s = 0.f;
                for (int cc = 0; cc < CH; ++cc) s += wr[cc] * av[h * CH + cc];
                v = s;
            } else if (n < NC) {
                v = W[(size_t)k * NC + n];
            }
        }
        split2(v, hi8[j], lo8[j]);
    }
    size_t o = ((size_t)gid) * 8;
#pragma unroll
    for (int j = 0; j < 8; ++j) { fhi[o + j] = hi8[j]; flo[o + j] = lo8[j]; }
}

#define SEG0 (PK0 * NT_HID * 64)
#define SEGH (PKH * NT_HID * 64)
#define SEGO (PKO * NT_HEAD * 64)

__global__ void convall_k(
    const float* W0, const float* W1, const float* W2, const float* W3, const float* Wh,
    const float* as0, const float* as1, const float* as2, const float* as3,
    const float* ad0, const float* ad1, const float* ad2, const float* ad3,
    ushort* f0h, ushort* f0l, ushort* f1h, ushort* f1l, ushort* f2h, ushort* f2l,
    ushort* f3h, ushort* f3l, ushort* fhh, ushort* fhl) {
    int gid = blockIdx.x * 256 + threadIdx.x;
    if (gid < SEG0) { convw_one(W0, as0, ad0, IN_CH, DD, NT_HID, f0h, f0l, gid); return; }
    gid -= SEG0;
    if (gid < SEGH) { convw_one(W1, as1, ad1, DD, DD, NT_HID, f1h, f1l, gid); return; }
    gid -= SEGH;
    if (gid < SEGH) { convw_one(W2, as2, ad2, DD, DD, NT_HID, f2h, f2l, gid); return; }
    gid -= SEGH;
    if (gid < SEGH) { convw_one(W3, as3, ad3, DD, DD, NT_HID, f3h, f3l, gid); return; }
    gid -= SEGH;
    if (gid < SEGO) { convw_one(Wh, nullptr, nullptr, DD, OUTW, NT_HEAD, fhh, fhl, gid); }
}

// ---------------- MFMA GEMM, M=128, BK=64, swizzled A LDS, TG=6 ---------
// R19: global_load_lds width=16 staging; 1D y-adjacent grid (R7-proven, 386us).
// R21: DB flag = 2-phase LDS double-buffer (T3 minimum recipe): issue tile
// pp+1's global_load_lds into the other buffer BEFORE computing tile pp, so
// the vmcnt(0) drain at the end-of-iter barrier lands after compute and the
// staging latency hides under MFMA. Hidden GEMM: DB (2x30720B <= 64KB).
// Head GEMM: single-buffered (2x57KB would exceed 64KB).
// R20 lesson: TG=3 regressed (doubled A-traffic, halved B-reuse) -> TG=6.

template<bool USE3, int TG, bool DB>
__global__ __launch_bounds__(256) void gemm4_k(
    const ushort* __restrict__ Ahi, const ushort* __restrict__ Alo, int kpairs,
    const ushort* __restrict__ Bhi, const ushort* __restrict__ Blo, int NTtot, int statsY,
    ushort* __restrict__ Cb16, float* __restrict__ as_, float* __restrict__ ad_,
    float* __restrict__ C, int ldc, int ncguard, const float* __restrict__ bias) {
    extern __shared__ ushort smem[];
    // per-buffer layout: AlH [2][8][512] | BlH [2][TG][512] | EXT
    const int BUFE = 8192 + 2 * TG * 512 + (USE3 ? (8192 + 2 * TG * 512) : 2 * 512);

    int tid = threadIdx.x;
    int ngy = NTtot / TG;
    int m0 = (blockIdx.x / ngy) * 128;
    int by = blockIdx.x % ngy;
    int t0 = by * TG;
    bool sg = (by == statsY);

    f32x4 acc[2][TG];
#pragma unroll
    for (int mt = 0; mt < 2; ++mt)
#pragma unroll
        for (int t = 0; t < TG; ++t) acc[mt][t] = (f32x4){0.f, 0.f, 0.f, 0.f};

    int w = tid >> 6, lane = tid & 63;
    int csA = (lane ^ ((lane >> 4) << 1)) * 8;

    // A-stage source mapping for this lane (slot = lane of each LDS row)
    int kqA = lane >> 4;
    int m15 = (lane ^ (kqA << 1)) & 15;

    auto stage = [&](int pp, ushort* base) {
        ushort* AlH_ = base;
        ushort* BlH_ = base + 8192;
        ushort* EXT_ = base + 8192 + 2 * TG * 512;
        ushort* AlL_ = EXT_;
        ushort* BlL_ = EXT_ + 8192;
        ushort* BstL_ = EXT_;
        int nArows = USE3 ? 32 : 16;
        for (int r = w; r < nArows; r += 4) {
            int hl = r >> 4;
            int panel = (r >> 3) & 1;
            int mrow16 = r & 7;
            int gm = m0 + mrow16 * 16 + m15;
            if (gm > N_NODES - 1) gm = N_NODES - 1;
            const ushort* g = (hl ? Alo : Ahi) + (size_t)gm * LDA + pp * 64 + panel * 32 + kqA * 8;
            ushort* l = (hl ? AlL_ : AlH_) + (panel * 8 + mrow16) * 512;
            ld_lds16(g, l);
        }
        for (int r = w; r < 2 * TG; r += 4) {
            int panel = r / TG, t = r % TG;
            size_t row = (size_t)((pp * 2 + panel) * NTtot + t0 + t) * 512;
            ld_lds16(Bhi + row + lane * 8, &BlH_[r * 512]);
            if (USE3) ld_lds16(Blo + row + lane * 8, &BlL_[r * 512]);
        }
        if (!USE3 && sg && w < 2) {
            int panel = w;
            size_t row = (size_t)((pp * 2 + panel) * NTtot + t0 + TG - 1) * 512;
            ld_lds16(Blo + row + lane * 8, &BstL_[panel * 512]);
        }
    };

    auto compute = [&](ushort* base) {
        ushort* AlH_ = base;
        ushort* BlH_ = base + 8192;
        ushort* EXT_ = base + 8192 + 2 * TG * 512;
        ushort* AlL_ = EXT_;
        ushort* BlL_ = EXT_ + 8192;
        ushort* BstL_ = EXT_;
#pragma unroll
        for (int panel = 0; panel < 2; ++panel) {
            bf16x8 a0 = *(const bf16x8*)&AlH_[panel * 4096 + (2 * w) * 512 + csA];
            bf16x8 a1 = *(const bf16x8*)&AlH_[panel * 4096 + (2 * w + 1) * 512 + csA];
            bf16x8 l0, l1;
            if (USE3) {
                l0 = *(const bf16x8*)&AlL_[panel * 4096 + (2 * w) * 512 + csA];
                l1 = *(const bf16x8*)&AlL_[panel * 4096 + (2 * w + 1) * 512 + csA];
            }
#pragma unroll
            for (int t = 0; t < TG; ++t) {
                bf16x8 bh = *(const bf16x8*)&BlH_[(panel * TG + t) * 512 + lane * 8];
                acc[0][t] = __builtin_amdgcn_mfma_f32_16x16x32_bf16(a0, bh, acc[0][t], 0, 0, 0);
                acc[1][t] = __builtin_amdgcn_mfma_f32_16x16x32_bf16(a1, bh, acc[1][t], 0, 0, 0);
                if (USE3) {
                    bf16x8 bl = *(const bf16x8*)&BlL_[(panel * TG + t) * 512 + lane * 8];
                    acc[0][t] = __builtin_amdgcn_mfma_f32_16x16x32_bf16(a0, bl, acc[0][t], 0, 0, 0);
                    acc[1][t] = __builtin_amdgcn_mfma_f32_16x16x32_bf16(a1, bl, acc[1][t], 0, 0, 0);
                    acc[0][t] = __builtin_amdgcn_mfma_f32_16x16x32_bf16(l0, bh, acc[0][t], 0, 0, 0);
                    acc[1][t] = __builtin_amdgcn_mfma_f32_16x16x32_bf16(l1, bh, acc[1][t], 0, 0, 0);
                } else if (t == TG - 1 && sg) {
                    bf16x8 bst = *(const bf16x8*)&BstL_[panel * 512 + lane * 8];
                    acc[0][t] = __builtin_amdgcn_mfma_f32_16x16x32_bf16(a0, bst, acc[0][t], 0, 0, 0);
                    acc[1][t] = __builtin_amdgcn_mfma_f32_16x16x32_bf16(a1, bst, acc[1][t], 0, 0, 0);
                }
            }
        }
    };

    if constexpr (DB) {
        stage(0, smem);
        __syncthreads();
        for (int pp = 0; pp < kpairs; ++pp) {
            ushort* cur = smem + (pp & 1) * BUFE;
            if (pp + 1 < kpairs) stage(pp + 1, smem + ((pp + 1) & 1) * BUFE);
            compute(cur);
            __syncthreads();   // drains vmcnt -> next buffer staged; cur reusable
        }
    } else {
        for (int pp = 0; pp < kpairs; ++pp) {
            stage(pp, smem);
            __syncthreads();
            compute(smem);
            __syncthreads();
        }
    }

    int col = lane & 15;
#pragma unroll
    for (int mt = 0; mt < 2; ++mt) {
        int rbase = m0 + (2 * w + mt) * 16 + ((lane >> 4) << 2);
#pragma unroll
        for (int t = 0; t < TG; ++t) {
            int tg = t0 + t;
#pragma unroll
            for (int r = 0; r < 4; ++r) {
                int gm = rbase + r;
                if (gm >= N_NODES) continue;
                float v = acc[mt][t][r];
                if (C) {
                    int gn = tg * 16 + col;
                    if (gn < ncguard) C[(size_t)gm * ldc + gn] = v + bias[gn];
                } else if (tg < 17) {
                    __hip_bfloat16 bv = __float2bfloat16(v);
                    Cb16[(size_t)gm * LDB + tg * 16 + col] = *(ushort*)&bv;
                } else {
                    if (col < 8) as_[(size_t)gm * 8 + col] = v;
                    else         ad_[(size_t)gm * 8 + col - 8] = v;
                }
            }
        }
    }
}

// ---------------- fused softmax + gather-aggregate: 2 nodes / wave (R18) ----------

__global__ __launch_bounds__(64) void gat_k(
    const ushort* __restrict__ xb, const float* __restrict__ as_,
    const float* __restrict__ ad_, const int* __restrict__ rowp,
    const int* __restrict__ csr, const float* __restrict__ bias,
    ushort* __restrict__ outhi, ushort* __restrict__ outlo) {
    int lane = threadIdx.x;
    int half = lane >> 5, l32 = lane & 31;
    int node = blockIdx.x * 2 + half;       // grid is exactly N/2
    int r0 = rowp[node], dg = rowp[node + 1] - r0;

    __shared__ float lex[2][32][9];
    __shared__ int   lsrc[2][32];

    float ad[8];
#pragma unroll
    for (int h = 0; h < 8; ++h) ad[h] = ad_[node * 8 + h];

    // this lane's 8 channels: cb..cb+7; they span at most 2 heads
    int cb = l32 * 8;
    int ha = cb / 33;
    int hb = (cb + 7) / 33;
    bool mm[8];
#pragma unroll
    for (int j = 0; j < 8; ++j) mm[j] = ((cb + j) / 33) != ha;

    float a0[8];
#pragma unroll
    for (int j = 0; j < 8; ++j) a0[j] = 0.f;
    float a1[4] = {0.f, 0.f, 0.f, 0.f};   // tail: even l32 ch 256-259, odd 260-263
    float sm[8] = {0.f, 0.f, 0.f, 0.f, 0.f, 0.f, 0.f, 0.f};

    int mych = (dg + 31) >> 5;
    int och = __shfl_xor(mych, 32, 64);
    int maxch = mych > och ? mych : och;

    for (int c = 0; c < maxch; ++c) {
        int base = c << 5, j = base + l32;
        int s = node;
        float p8[8];
#pragma unroll
        for (int h = 0; h < 8; ++h) p8[h] = 0.f;
        if (j < dg) {
            s = csr[r0 + j];
            const float* ap = as_ + (size_t)s * 8;
#pragma unroll
            for (int h = 0; h < 8; ++h) {
                float e = ap[h] + ad[h];
                e = e > 0.f ? e : NEG * e;
                float p = __expf(e);
                p8[h] = p;
                sm[h] += p;
            }
        }
        lsrc[half][l32] = s * LDB;   // pre-scaled row offset (ushorts)
#pragma unroll
        for (int h = 0; h < 8; ++h) lex[half][l32][h] = p8[h];
        __builtin_amdgcn_wave_barrier();

        int rem = dg - base;
        int cnt = rem < 0 ? 0 : (rem > 32 ? 32 : rem);
        int cnt4 = (cnt + 3) & ~3;
        for (int jj = 0; jj < cnt4; jj += 4) {
            int o0 = lsrc[half][jj + 0], o1 = lsrc[half][jj + 1];
            int o2 = lsrc[half][jj + 2], o3 = lsrc[half][jj + 3];
            const uint4* p0 = (const uint4*)(xb + (size_t)(unsigned)o0);
            const uint4* p1 = (const uint4*)(xb + (size_t)(unsigned)o1);
            const uint4* p2 = (const uint4*)(xb + (size_t)(unsigned)o2);
            const uint4* p3 = (const uint4*)(xb + (size_t)(unsigned)o3);
            uint4 v0 = p0[l32], v1 = p1[l32], v2 = p2[l32], v3 = p3[l32];
            // tail: uint2 slots 64/65 (ch 256-263), parity-split broadcast
            const uint2* q0 = (const uint2*)p0;
            const uint2* q1 = (const uint2*)p1;
            const uint2* q2 = (const uint2*)p2;
            const uint2* q3 = (const uint2*)p3;
            uint2 t0 = q0[64 + (l32 & 1)], t1 = q1[64 + (l32 & 1)];
            uint2 t2 = q2[64 + (l32 & 1)], t3 = q3[64 + (l32 & 1)];
#pragma unroll
            for (int e = 0; e < 4; ++e) {
                const float* xr = lex[half][jj + e];
                float xa = xr[ha], xbv = xr[hb], x7 = xr[7];
                uint4 v = (e == 0) ? v0 : (e == 1) ? v1 : (e == 2) ? v2 : v3;
                uint2 t = (e == 0) ? t0 : (e == 1) ? t1 : (e == 2) ? t2 : t3;
                a0[0] += (mm[0] ? xbv : xa) * bflo(v.x);
                a0[1] += (mm[1] ? xbv : xa) * bfhi(v.x);
                a0[2] += (mm[2] ? xbv : xa) * bflo(v.y);
                a0[3] += (mm[3] ? xbv : xa) * bfhi(v.y);
                a0[4] += (mm[4] ? xbv : xa) * bflo(v.z);
                a0[5] += (mm[5] ? xbv : xa) * bfhi(v.z);
                a0[6] += (mm[6] ? xbv : xa) * bflo(v.w);
                a0[7] += (mm[7] ? xbv : xa) * bfhi(v.w);
                a1[0] += x7 * bflo(t.x);
                a1[1] += x7 * bfhi(t.x);
                a1[2] += x7 * bflo(t.y);
                a1[3] += x7 * bfhi(t.y);
            }
        }
        __builtin_amdgcn_wave_barrier();
    }

    // deferred sum reduction -> iv[8]; xor offsets <=16 stay within each half
    float iv[8];
#pragma unroll
    for (int h = 0; h < 8; ++h) {
        float s = sm[h];
        for (int off = 16; off; off >>= 1) s += __shfl_xor(s, off, 64);
        iv[h] = 1.0f / (s + 1e-16f);
    }

    // epilogue: normalize, bias + elu, bf16 out (hi; lo when requested)
    {
        float iva = iv[ha], ivb = iv[hb];
        ushort hi8[8], lo8[8];
        float4 b0 = *(const float4*)(bias + cb);
        float4 b1 = *(const float4*)(bias + cb + 4);
        float bv4[8] = {b0.x, b0.y, b0.z, b0.w, b1.x, b1.y, b1.z, b1.w};
#pragma unroll
        for (int j = 0; j < 8; ++j) {
            float v = a0[j] * (mm[j] ? ivb : iva) + bv4[j];
            v = v > 0.f ? v : (__expf(v) - 1.f);
            split2(v, hi8[j], lo8[j]);
        }
        size_t o = (size_t)node * LDA + cb;
        *(ushort4*)(outhi + o) = *(ushort4*)&hi8[0];
        *(ushort4*)(outhi + o + 4) = *(ushort4*)&hi8[4];
        if (outlo) {
            *(ushort4*)(outlo + o) = *(ushort4*)&lo8[0];
            *(ushort4*)(outlo + o + 4) = *(ushort4*)&lo8[4];
        }
    }
    if (l32 < 2) {
        ushort hi4[4], lo4[4];
        float4 bt = *(const float4*)(bias + 256 + l32 * 4);
        float bv4[4] = {bt.x, bt.y, bt.z, bt.w};
#pragma unroll
        for (int j = 0; j < 4; ++j) {
            float v = a1[j] * iv[7] + bv4[j];
            v = v > 0.f ? v : (__expf(v) - 1.f);
            split2(v, hi4[j], lo4[j]);
        }
        size_t o = (size_t)node * LDA + 256 + l32 * 4;
        *(ushort4*)(outhi + o) = *(ushort4*)hi4;
        if (outlo) *(ushort4*)(outlo + o) = *(ushort4*)lo4;
    } else if (l32 < 9) {
        ushort4 z = {0, 0, 0, 0};
        size_t o = (size_t)node * LDA + 264 + (l32 - 2) * 8;
        *(ushort4*)(outhi + o) = z;
        *(ushort4*)(outhi + o + 4) = z;
        if (outlo) {
            *(ushort4*)(outlo + o) = z;
            *(ushort4*)(outlo + o + 4) = z;
        }
    }
}

// ---------------- launch ----------------

extern "C" void kernel_launch(void* const* d_in, const int* in_sizes, int n_in,
                              void* d_out, int out_size, void* d_ws, size_t ws_size,
                              hipStream_t stream) {
    const float* x  = (const float*)d_in[0];
    const int*   ei = (const int*)d_in[1];
    const float* W[4]  = {(const float*)d_in[2],  (const float*)d_in[6],
                          (const float*)d_in[10], (const float*)d_in[14]};
    const float* As[4] = {(const float*)d_in[3],  (const float*)d_in[7],
                          (const float*)d_in[11], (const float*)d_in[15]};
    const float* Ad[4] = {(const float*)d_in[4],  (const float*)d_in[8],
                          (const float*)d_in[12], (const float*)d_in[16]};
    const float* Bb[4] = {(const float*)d_in[5],  (const float*)d_in[9],
                          (const float*)d_in[13], (const float*)d_in[17]};
    const float* Wh = (const float*)d_in[18];
    const float* bh = (const float*)d_in[19];

    // ---- workspace carve ----
    char* p = (char*)d_ws;
    ushort* hBb  = (ushort*)p;          p += (size_t)N_NODES * LDB * 2;
    ushort* hAhi = (ushort*)p;          p += (size_t)N_NODES * LDA * 2;
    ushort* hAlo = (ushort*)p;          p += (size_t)N_NODES * LDA * 2;
    float* as_  = (float*)p;            p += (size_t)N_NODES * HEADS * 4;
    float* ad_  = (float*)p;            p += (size_t)N_NODES * HEADS * 4;
    const int wsz0 = PK0 * NT_HID * 512;
    const int wszH = PKH * NT_HID * 512;
    const int wszO = PKO * NT_HEAD * 512;
    ushort* wfhi[4]; ushort* wflo[4];
    for (int l = 0; l < 4; ++l) {
        int sz = (l == 0) ? wsz0 : wszH;
        wfhi[l] = (ushort*)p; p += (size_t)sz * 2;
        wflo[l] = (ushort*)p; p += (size_t)sz * 2;
    }
    ushort* whhi = (ushort*)p; p += (size_t)wszO * 2;
    ushort* whlo = (ushort*)p; p += (size_t)wszO * 2;
    int* deg  = (int*)p;  p += N_NODES * 4;
    int* cur  = (int*)p;  p += N_NODES * 4;
    int* rowp = (int*)p;  p += (N_NODES + 1) * 4;
    int* csr  = (int*)p;  p += (size_t)TOT_E * 4;

    // ---- CSR build ----
    hipMemsetAsync(deg, 0, sizeof(int) * 2 * N_NODES, stream);  // deg + cur
    int egrid = (TOT_E + 255) / 256;
    deg_k<<<egrid, 256, 0, stream>>>(ei, deg);
    scan_k<<<1, 1024, 0, stream>>>(deg, rowp);
    fill_k<<<egrid, 256, 0, stream>>>(ei, rowp, cur, csr);

    // ---- weight + input conversion (single launch for all weights) ----
    splitx_k<<<(N_NODES * IN_CH + 255) / 256, 256, 0, stream>>>(x, hAhi);
    {
        int tot = SEG0 + 3 * SEGH + SEGO;
        convall_k<<<(tot + 255) / 256, 256, 0, stream>>>(
            W[0], W[1], W[2], W[3], Wh,
            As[0], As[1], As[2], As[3],
            Ad[0], Ad[1], Ad[2], Ad[3],
            wfhi[0], wflo[0], wfhi[1], wflo[1], wfhi[2], wflo[2],
            wfhi[3], wflo[3], whhi, whlo);
    }

    int nmb = (N_NODES + 127) / 128;              // 157
    int gG = nmb * (NT_HID / 6);                  // 471, y-adjacent
    int gO = nmb * (NT_HEAD / 6);                 // 314
    size_t smHid = (size_t)(8192 + 2 * 6 * 512 + 2 * 512) * 2 * 2;         // 61440 B (2 bufs)
    size_t smHead = (size_t)(8192 + 2 * 6 * 512 + 8192 + 2 * 6 * 512) * 2; // 57344 B (1 buf)

    for (int l = 0; l < 4; ++l) {
        int kpairs = (l == 0) ? PK0 / 2 : PKH / 2;
        gemm4_k<false, 6, true><<<gG, 256, smHid, stream>>>(hAhi, nullptr, kpairs,
                                                            wfhi[l], wflo[l], NT_HID, 2,
                                                            hBb, as_, ad_, nullptr, 0, 0, nullptr);
        gat_k<<<N_NODES / 2, 64, 0, stream>>>(hBb, as_, ad_, rowp, csr, Bb[l],
                                              hAhi, (l == 3) ? hAlo : nullptr);
    }

    // head readout (3-term) -> fp32 out [N, 132]
    gemm4_k<true, 6, false><<<gO, 256, smHead, stream>>>(hAhi, hAlo, PKO / 2,
                                                         whhi, whlo, NT_HEAD, -1,
                                                         nullptr, nullptr, nullptr,
                                                         (float*)d_out, OUTW, OUTW, bh);
}

// Round 11
// 379.277 us; speedup vs baseline: 1.0466x; 1.0052x over previous
//
#include <hip/hip_runtime.h>
#include <hip/hip_bf16.h>

#define N_NODES 20000
#define N_EDGES 320000
#define TOT_E   (N_EDGES + N_NODES)   // 340000 with self loops
#define IN_CH   128
#define HEADS   8
#define CH      33
#define DD      264                   // HEADS*CH
#define OUTW    132
#define NEG     0.2f

#define LDB     272                   // bf16 payload row stride (34 uint4 slots)
#define LDA     320                   // hA bf16 row stride, K padded to 10*32
#define NT_HID  18                    // 17 payload tiles + 1 stats tile [was|wad]
#define NT_HEAD 10                    // head gemm tiles (132 -> 160, zero-padded)
#define PK0     4                     // layer0 K panels (128 exact)
#define PKH     10                    // weight buffer K panels (layout; 9 used)
#define PKO     10
#define NP_HID  9                     // K panels actually processed (264 <= 288)
#define NP_HEAD 9

typedef unsigned short ushort;
typedef unsigned int uint32;
typedef short bf16x8 __attribute__((ext_vector_type(8)));
typedef float f32x4  __attribute__((ext_vector_type(4)));

__device__ inline void split2(float v, ushort& hi, ushort& lo) {
    __hip_bfloat16 h = __float2bfloat16(v);
    float r = v - __bfloat162float(h);
    __hip_bfloat16 l = __float2bfloat16(r);
    hi = *(ushort*)&h;
    lo = *(ushort*)&l;
}

__device__ inline float bf2f(ushort u) {
    union { unsigned int i; float f; } c;
    c.i = ((unsigned int)u) << 16;
    return c.f;
}

// low ushort of dword -> f32 (shift), high ushort -> f32 (free AND)
__device__ inline float bflo(uint32 d) {
    union { unsigned int i; float f; } c;
    c.i = d << 16;
    return c.f;
}
__device__ inline float bfhi(uint32 d) {
    union { unsigned int i; float f; } c;
    c.i = d & 0xffff0000u;
    return c.f;
}

// async global->LDS, 16B per lane; LDS dst is wave-uniform base + lane*16
__device__ __forceinline__ void ld_lds16(const ushort* g, ushort* l) {
    __builtin_amdgcn_global_load_lds(
        (const __attribute__((address_space(1))) void*)g,
        (__attribute__((address_space(3))) void*)l, 16, 0, 0);
}

// ---------------- CSR build ----------------

__global__ void deg_k(const int* __restrict__ ei, int* __restrict__ deg) {
    int e = blockIdx.x * 256 + threadIdx.x;
    if (e >= TOT_E) return;
    int dst = (e < N_EDGES) ? ei[N_EDGES + e] : (e - N_EDGES);
    atomicAdd(&deg[dst], 1);
}

__global__ __launch_bounds__(1024) void scan_k(const int* __restrict__ deg,
                                               int* __restrict__ rowp) {
    __shared__ int part[1024];
    const int PER = 20;
    int t = threadIdx.x;
    int base = t * PER;
    int s = 0;
    for (int i = 0; i < PER; ++i) {
        int idx = base + i;
        if (idx < N_NODES) s += deg[idx];
    }
    part[t] = s;
    __syncthreads();
    for (int off = 1; off < 1024; off <<= 1) {
        int v = 0;
        if (t >= off) v = part[t - off];
        __syncthreads();
        part[t] += v;
        __syncthreads();
    }
    int run = part[t] - s;
    for (int i = 0; i < PER; ++i) {
        int idx = base + i;
        if (idx < N_NODES) { rowp[idx] = run; run += deg[idx]; }
    }
    if (t == 1023) rowp[N_NODES] = part[1023];
}

__global__ void fill_k(const int* __restrict__ ei, const int* __restrict__ rowp,
                       int* __restrict__ cur, int* __restrict__ csr) {
    int e = blockIdx.x * 256 + threadIdx.x;
    if (e >= TOT_E) return;
    int src, dst;
    if (e < N_EDGES) { src = ei[e]; dst = ei[N_EDGES + e]; }
    else             { src = dst = e - N_EDGES; }
    int p = atomicAdd(&cur[dst], 1);
    csr[rowp[dst] + p] = src;
}

// ---------------- input x -> bf16 (into hAhi, stride LDA) ----------------

__global__ void splitx_k(const float* __restrict__ x, ushort* __restrict__ ahi) {
    int idx = blockIdx.x * 256 + threadIdx.x;
    if (idx >= N_NODES * IN_CH) return;
    int n = idx >> 7, k = idx & 127;
    __hip_bfloat16 h = __float2bfloat16(x[idx]);
    ahi[(size_t)n * LDA + k] = *(ushort*)&h;
}

// ---------------- all weights -> fragment-ordered hi/lo bf16, one launch ----------------

__device__ void convw_one(const float* W, const float* a_s, const float* a_d,
                          int K, int NC, int NT, ushort* fhi, ushort* flo, int gid) {
    int p = gid / (NT * 64);
    int rem = gid % (NT * 64);
    int t = rem >> 6, c = rem & 63;
    int kq = c >> 4, m = c & 15;
    int n = t * 16 + m;
    bool stats = (a_s != nullptr) && (t == NT - 1);
    ushort hi8[8], lo8[8];
#pragma unroll
    for (int j = 0; j < 8; ++j) {
        int k = p * 32 + kq * 8 + j;
        float v = 0.f;
        if (k < K) {
            if (stats) {
                const float* av = (m < 8) ? a_s : a_d;
                int h = (m < 8) ? m : m - 8;
                const float* wr = W + (size_t)k * NC + h * CH;
                float s = 0.f;
                for (int cc = 0; cc < CH; ++cc) s += wr[cc] * av[h * CH + cc];
                v = s;
            } else if (n < NC) {
                v = W[(size_t)k * NC + n];
            }
        }
        split2(v, hi8[j], lo8[j]);
    }
    size_t o = ((size_t)gid) * 8;
#pragma unroll
    for (int j = 0; j < 8; ++j) { fhi[o + j] = hi8[j]; flo[o + j] = lo8[j]; }
}

#define SEG0 (PK0 * NT_HID * 64)
#define SEGH (PKH * NT_HID * 64)
#define SEGO (PKO * NT_HEAD * 64)

__global__ void convall_k(
    const float* W0, const float* W1, const float* W2, const float* W3, const float* Wh,
    const float* as0, const float* as1, const float* as2, const float* as3,
    const float* ad0, const float* ad1, const float* ad2, const float* ad3,
    ushort* f0h, ushort* f0l, ushort* f1h, ushort* f1l, ushort* f2h, ushort* f2l,
    ushort* f3h, ushort* f3l, ushort* fhh, ushort* fhl) {
    int gid = blockIdx.x * 256 + threadIdx.x;
    if (gid < SEG0) { convw_one(W0, as0, ad0, IN_CH, DD, NT_HID, f0h, f0l, gid); return; }
    gid -= SEG0;
    if (gid < SEGH) { convw_one(W1, as1, ad1, DD, DD, NT_HID, f1h, f1l, gid); return; }
    gid -= SEGH;
    if (gid < SEGH) { convw_one(W2, as2, ad2, DD, DD, NT_HID, f2h, f2l, gid); return; }
    gid -= SEGH;
    if (gid < SEGH) { convw_one(W3, as3, ad3, DD, DD, NT_HID, f3h, f3l, gid); return; }
    gid -= SEGH;
    if (gid < SEGO) { convw_one(Wh, nullptr, nullptr, DD, OUTW, NT_HEAD, fhh, fhl, gid); }
}

// ---------------- MFMA GEMM, M=128, BK=64, swizzled A LDS ---------
// R19: global_load_lds width=16 staging; 1D y-adjacent grid.
// R21: 2-phase LDS double-buffer for hidden (DB flag).
// R22: K-trim -- npanels arg replaces kpairs; odd counts handled by a tail
// single-panel unit (264 actual K -> 9 panels of 32, not 10: kills the 17%
// zero-padding MFMA/staging). Head: NT_HEAD 12->10 with TG=5 (160 >= 132
// cols, ngy stays 2 so A-traffic is unchanged -- R20 lesson).

template<bool USE3, int TG, bool DB>
__global__ __launch_bounds__(256) void gemm4_k(
    const ushort* __restrict__ Ahi, const ushort* __restrict__ Alo, int npanels,
    const ushort* __restrict__ Bhi, const ushort* __restrict__ Blo, int NTtot, int statsY,
    ushort* __restrict__ Cb16, float* __restrict__ as_, float* __restrict__ ad_,
    float* __restrict__ C, int ldc, int ncguard, const float* __restrict__ bias) {
    extern __shared__ ushort smem[];
    // per-buffer layout: AlH [2][8][512] | BlH [2][TG][512] | EXT
    const int BUFE = 8192 + 2 * TG * 512 + (USE3 ? (8192 + 2 * TG * 512) : 2 * 512);

    int tid = threadIdx.x;
    int ngy = NTtot / TG;
    int m0 = (blockIdx.x / ngy) * 128;
    int by = blockIdx.x % ngy;
    int t0 = by * TG;
    bool sg = (by == statsY);

    f32x4 acc[2][TG];
#pragma unroll
    for (int mt = 0; mt < 2; ++mt)
#pragma unroll
        for (int t = 0; t < TG; ++t) acc[mt][t] = (f32x4){0.f, 0.f, 0.f, 0.f};

    int w = tid >> 6, lane = tid & 63;
    int csA = (lane ^ ((lane >> 4) << 1)) * 8;

    // A-stage source mapping for this lane (slot = lane of each LDS row)
    int kqA = lane >> 4;
    int m15 = (lane ^ (kqA << 1)) & 15;

    // stage panels [kp0, kp0+npan) into buffer slots [0, npan); npan in {1,2}
    auto stage = [&](int kp0, int npan, ushort* base) {
        ushort* AlH_ = base;
        ushort* BlH_ = base + 8192;
        ushort* EXT_ = base + 8192 + 2 * TG * 512;
        ushort* AlL_ = EXT_;
        ushort* BlL_ = EXT_ + 8192;
        ushort* BstL_ = EXT_;
        int pm = npan << 3;                     // A rows per hi/lo half
        int nArows = USE3 ? 2 * pm : pm;
        for (int r = w; r < nArows; r += 4) {
            int hl = (r >= pm) ? 1 : 0;
            int rr = r - hl * pm;
            int panel = rr >> 3;
            int mrow16 = rr & 7;
            int gm = m0 + mrow16 * 16 + m15;
            if (gm > N_NODES - 1) gm = N_NODES - 1;
            const ushort* g = (hl ? Alo : Ahi) + (size_t)gm * LDA + (kp0 + panel) * 32 + kqA * 8;
            ushort* l = (hl ? AlL_ : AlH_) + (panel * 8 + mrow16) * 512;
            ld_lds16(g, l);
        }
        for (int r = w; r < npan * TG; r += 4) {
            int panel = (r >= TG) ? 1 : 0;
            int t = r - panel * TG;
            size_t row = (size_t)((kp0 + panel) * NTtot + t0 + t) * 512;
            ld_lds16(Bhi + row + lane * 8, &BlH_[(panel * TG + t) * 512]);
            if (USE3) ld_lds16(Blo + row + lane * 8, &BlL_[(panel * TG + t) * 512]);
        }
        if (!USE3 && sg && w < npan) {
            int panel = w;
            size_t row = (size_t)((kp0 + panel) * NTtot + t0 + TG - 1) * 512;
            ld_lds16(Blo + row + lane * 8, &BstL_[panel * 512]);
        }
    };

    auto compute = [&](int npan, ushort* base) {
        ushort* AlH_ = base;
        ushort* BlH_ = base + 8192;
        ushort* EXT_ = base + 8192 + 2 * TG * 512;
        ushort* AlL_ = EXT_;
        ushort* BlL_ = EXT_ + 8192;
        ushort* BstL_ = EXT_;
        for (int panel = 0; panel < npan; ++panel) {
            bf16x8 a0 = *(const bf16x8*)&AlH_[panel * 4096 + (2 * w) * 512 + csA];
            bf16x8 a1 = *(const bf16x8*)&AlH_[panel * 4096 + (2 * w + 1) * 512 + csA];
            bf16x8 l0, l1;
            if (USE3) {
                l0 = *(const bf16x8*)&AlL_[panel * 4096 + (2 * w) * 512 + csA];
                l1 = *(const bf16x8*)&AlL_[panel * 4096 + (2 * w + 1) * 512 + csA];
            }
#pragma unroll
            for (int t = 0; t < TG; ++t) {
                bf16x8 bh = *(const bf16x8*)&BlH_[(panel * TG + t) * 512 + lane * 8];
                acc[0][t] = __builtin_amdgcn_mfma_f32_16x16x32_bf16(a0, bh, acc[0][t], 0, 0, 0);
                acc[1][t] = __builtin_amdgcn_mfma_f32_16x16x32_bf16(a1, bh, acc[1][t], 0, 0, 0);
                if (USE3) {
                    bf16x8 bl = *(const bf16x8*)&BlL_[(panel * TG + t) * 512 + lane * 8];
                    acc[0][t] = __builtin_amdgcn_mfma_f32_16x16x32_bf16(a0, bl, acc[0][t], 0, 0, 0);
                    acc[1][t] = __builtin_amdgcn_mfma_f32_16x16x32_bf16(a1, bl, acc[1][t], 0, 0, 0);
                    acc[0][t] = __builtin_amdgcn_mfma_f32_16x16x32_bf16(l0, bh, acc[0][t], 0, 0, 0);
                    acc[1][t] = __builtin_amdgcn_mfma_f32_16x16x32_bf16(l1, bh, acc[1][t], 0, 0, 0);
                } else if (t == TG - 1 && sg) {
                    bf16x8 bst = *(const bf16x8*)&BstL_[panel * 512 + lane * 8];
                    acc[0][t] = __builtin_amdgcn_mfma_f32_16x16x32_bf16(a0, bst, acc[0][t], 0, 0, 0);
                    acc[1][t] = __builtin_amdgcn_mfma_f32_16x16x32_bf16(a1, bst, acc[1][t], 0, 0, 0);
                }
            }
        }
    };

    int npairs = npanels >> 1;
    int nunits = npairs + (npanels & 1);
    auto np_of = [&](int u) { return (u < npairs) ? 2 : 1; };

    if constexpr (DB) {
        stage(0, np_of(0), smem);
        __syncthreads();
        for (int u = 0; u < nunits; ++u) {
            ushort* curb = smem + (u & 1) * BUFE;
            if (u + 1 < nunits) stage(2 * (u + 1), np_of(u + 1), smem + ((u + 1) & 1) * BUFE);
            compute(np_of(u), curb);
            __syncthreads();   // drains vmcnt -> next buffer staged; cur reusable
        }
    } else {
        for (int u = 0; u < nunits; ++u) {
            stage(2 * u, np_of(u), smem);
            __syncthreads();
            compute(np_of(u), smem);
            __syncthreads();
        }
    }

    int col = lane & 15;
#pragma unroll
    for (int mt = 0; mt < 2; ++mt) {
        int rbase = m0 + (2 * w + mt) * 16 + ((lane >> 4) << 2);
#pragma unroll
        for (int t = 0; t < TG; ++t) {
            int tg = t0 + t;
#pragma unroll
            for (int r = 0; r < 4; ++r) {
                int gm = rbase + r;
                if (gm >= N_NODES) continue;
                float v = acc[mt][t][r];
                if (C) {
                    int gn = tg * 16 + col;
                    if (gn < ncguard) C[(size_t)gm * ldc + gn] = v + bias[gn];
                } else if (tg < 17) {
                    __hip_bfloat16 bv = __float2bfloat16(v);
                    Cb16[(size_t)gm * LDB + tg * 16 + col] = *(ushort*)&bv;
                } else {
                    if (col < 8) as_[(size_t)gm * 8 + col] = v;
                    else         ad_[(size_t)gm * 8 + col - 8] = v;
                }
            }
        }
    }
}

// ---------------- fused softmax + gather-aggregate: 2 nodes / wave (R18) ----------

__global__ __launch_bounds__(64) void gat_k(
    const ushort* __restrict__ xb, const float* __restrict__ as_,
    const float* __restrict__ ad_, const int* __restrict__ rowp,
    const int* __restrict__ csr, const float* __restrict__ bias,
    ushort* __restrict__ outhi, ushort* __restrict__ outlo) {
    int lane = threadIdx.x;
    int half = lane >> 5, l32 = lane & 31;
    int node = blockIdx.x * 2 + half;       // grid is exactly N/2
    int r0 = rowp[node], dg = rowp[node + 1] - r0;

    __shared__ float lex[2][32][9];
    __shared__ int   lsrc[2][32];

    float ad[8];
#pragma unroll
    for (int h = 0; h < 8; ++h) ad[h] = ad_[node * 8 + h];

    // this lane's 8 channels: cb..cb+7; they span at most 2 heads
    int cb = l32 * 8;
    int ha = cb / 33;
    int hb = (cb + 7) / 33;
    bool mm[8];
#pragma unroll
    for (int j = 0; j < 8; ++j) mm[j] = ((cb + j) / 33) != ha;

    float a0[8];
#pragma unroll
    for (int j = 0; j < 8; ++j) a0[j] = 0.f;
    float a1[4] = {0.f, 0.f, 0.f, 0.f};   // tail: even l32 ch 256-259, odd 260-263
    float sm[8] = {0.f, 0.f, 0.f, 0.f, 0.f, 0.f, 0.f, 0.f};

    int mych = (dg + 31) >> 5;
    int och = __shfl_xor(mych, 32, 64);
    int maxch = mych > och ? mych : och;

    for (int c = 0; c < maxch; ++c) {
        int base = c << 5, j = base + l32;
        int s = node;
        float p8[8];
#pragma unroll
        for (int h = 0; h < 8; ++h) p8[h] = 0.f;
        if (j < dg) {
            s = csr[r0 + j];
            const float* ap = as_ + (size_t)s * 8;
#pragma unroll
            for (int h = 0; h < 8; ++h) {
                float e = ap[h] + ad[h];
                e = e > 0.f ? e : NEG * e;
                float p = __expf(e);
                p8[h] = p;
                sm[h] += p;
            }
        }
        lsrc[half][l32] = s * LDB;   // pre-scaled row offset (ushorts)
#pragma unroll
        for (int h = 0; h < 8; ++h) lex[half][l32][h] = p8[h];
        __builtin_amdgcn_wave_barrier();

        int rem = dg - base;
        int cnt = rem < 0 ? 0 : (rem > 32 ? 32 : rem);
        int cnt4 = (cnt + 3) & ~3;
        for (int jj = 0; jj < cnt4; jj += 4) {
            int o0 = lsrc[half][jj + 0], o1 = lsrc[half][jj + 1];
            int o2 = lsrc[half][jj + 2], o3 = lsrc[half][jj + 3];
            const uint4* p0 = (const uint4*)(xb + (size_t)(unsigned)o0);
            const uint4* p1 = (const uint4*)(xb + (size_t)(unsigned)o1);
            const uint4* p2 = (const uint4*)(xb + (size_t)(unsigned)o2);
            const uint4* p3 = (const uint4*)(xb + (size_t)(unsigned)o3);
            uint4 v0 = p0[l32], v1 = p1[l32], v2 = p2[l32], v3 = p3[l32];
            // tail: uint2 slots 64/65 (ch 256-263), parity-split broadcast
            const uint2* q0 = (const uint2*)p0;
            const uint2* q1 = (const uint2*)p1;
            const uint2* q2 = (const uint2*)p2;
            const uint2* q3 = (const uint2*)p3;
            uint2 t0 = q0[64 + (l32 & 1)], t1 = q1[64 + (l32 & 1)];
            uint2 t2 = q2[64 + (l32 & 1)], t3 = q3[64 + (l32 & 1)];
#pragma unroll
            for (int e = 0; e < 4; ++e) {
                const float* xr = lex[half][jj + e];
                float xa = xr[ha], xbv = xr[hb], x7 = xr[7];
                uint4 v = (e == 0) ? v0 : (e == 1) ? v1 : (e == 2) ? v2 : v3;
                uint2 t = (e == 0) ? t0 : (e == 1) ? t1 : (e == 2) ? t2 : t3;
                a0[0] += (mm[0] ? xbv : xa) * bflo(v.x);
                a0[1] += (mm[1] ? xbv : xa) * bfhi(v.x);
                a0[2] += (mm[2] ? xbv : xa) * bflo(v.y);
                a0[3] += (mm[3] ? xbv : xa) * bfhi(v.y);
                a0[4] += (mm[4] ? xbv : xa) * bflo(v.z);
                a0[5] += (mm[5] ? xbv : xa) * bfhi(v.z);
                a0[6] += (mm[6] ? xbv : xa) * bflo(v.w);
                a0[7] += (mm[7] ? xbv : xa) * bfhi(v.w);
                a1[0] += x7 * bflo(t.x);
                a1[1] += x7 * bfhi(t.x);
                a1[2] += x7 * bflo(t.y);
                a1[3] += x7 * bfhi(t.y);
            }
        }
        __builtin_amdgcn_wave_barrier();
    }

    // deferred sum reduction -> iv[8]; xor offsets <=16 stay within each half
    float iv[8];
#pragma unroll
    for (int h = 0; h < 8; ++h) {
        float s = sm[h];
        for (int off = 16; off; off >>= 1) s += __shfl_xor(s, off, 64);
        iv[h] = 1.0f / (s + 1e-16f);
    }

    // epilogue: normalize, bias + elu, bf16 out (hi; lo when requested)
    {
        float iva = iv[ha], ivb = iv[hb];
        ushort hi8[8], lo8[8];
        float4 b0 = *(const float4*)(bias + cb);
        float4 b1 = *(const float4*)(bias + cb + 4);
        float bv4[8] = {b0.x, b0.y, b0.z, b0.w, b1.x, b1.y, b1.z, b1.w};
#pragma unroll
        for (int j = 0; j < 8; ++j) {
            float v = a0[j] * (mm[j] ? ivb : iva) + bv4[j];
            v = v > 0.f ? v : (__expf(v) - 1.f);
            split2(v, hi8[j], lo8[j]);
        }
        size_t o = (size_t)node * LDA + cb;
        *(ushort4*)(outhi + o) = *(ushort4*)&hi8[0];
        *(ushort4*)(outhi + o + 4) = *(ushort4*)&hi8[4];
        if (outlo) {
            *(ushort4*)(outlo + o) = *(ushort4*)&lo8[0];
            *(ushort4*)(outlo + o + 4) = *(ushort4*)&lo8[4];
        }
    }
    if (l32 < 2) {
        ushort hi4[4], lo4[4];
        float4 bt = *(const float4*)(bias + 256 + l32 * 4);
        float bv4[4] = {bt.x, bt.y, bt.z, bt.w};
#pragma unroll
        for (int j = 0; j < 4; ++j) {
            float v = a1[j] * iv[7] + bv4[j];
            v = v > 0.f ? v : (__expf(v) - 1.f);
            split2(v, hi4[j], lo4[j]);
        }
        size_t o = (size_t)node * LDA + 256 + l32 * 4;
        *(ushort4*)(outhi + o) = *(ushort4*)hi4;
        if (outlo) *(ushort4*)(outlo + o) = *(ushort4*)lo4;
    } else if (l32 < 9) {
        ushort4 z = {0, 0, 0, 0};
        size_t o = (size_t)node * LDA + 264 + (l32 - 2) * 8;
        *(ushort4*)(outhi + o) = z;
        *(ushort4*)(outhi + o + 4) = z;
        if (outlo) {
            *(ushort4*)(outlo + o) = z;
            *(ushort4*)(outlo + o + 4) = z;
        }
    }
}

// ---------------- launch ----------------

extern "C" void kernel_launch(void* const* d_in, const int* in_sizes, int n_in,
                              void* d_out, int out_size, void* d_ws, size_t ws_size,
                              hipStream_t stream) {
    const float* x  = (const float*)d_in[0];
    const int*   ei = (const int*)d_in[1];
    const float* W[4]  = {(const float*)d_in[2],  (const float*)d_in[6],
                          (const float*)d_in[10], (const float*)d_in[14]};
    const float* As[4] = {(const float*)d_in[3],  (const float*)d_in[7],
                          (const float*)d_in[11], (const float*)d_in[15]};
    const float* Ad[4] = {(const float*)d_in[4],  (const float*)d_in[8],
                          (const float*)d_in[12], (const float*)d_in[16]};
    const float* Bb[4] = {(const float*)d_in[5],  (const float*)d_in[9],
                          (const float*)d_in[13], (const float*)d_in[17]};
    const float* Wh = (const float*)d_in[18];
    const float* bh = (const float*)d_in[19];

    // ---- workspace carve ----
    char* p = (char*)d_ws;
    ushort* hBb  = (ushort*)p;          p += (size_t)N_NODES * LDB * 2;
    ushort* hAhi = (ushort*)p;          p += (size_t)N_NODES * LDA * 2;
    ushort* hAlo = (ushort*)p;          p += (size_t)N_NODES * LDA * 2;
    float* as_  = (float*)p;            p += (size_t)N_NODES * HEADS * 4;
    float* ad_  = (float*)p;            p += (size_t)N_NODES * HEADS * 4;
    const int wsz0 = PK0 * NT_HID * 512;
    const int wszH = PKH * NT_HID * 512;
    const int wszO = PKO * NT_HEAD * 512;
    ushort* wfhi[4]; ushort* wflo[4];
    for (int l = 0; l < 4; ++l) {
        int sz = (l == 0) ? wsz0 : wszH;
        wfhi[l] = (ushort*)p; p += (size_t)sz * 2;
        wflo[l] = (ushort*)p; p += (size_t)sz * 2;
    }
    ushort* whhi = (ushort*)p; p += (size_t)wszO * 2;
    ushort* whlo = (ushort*)p; p += (size_t)wszO * 2;
    int* deg  = (int*)p;  p += N_NODES * 4;
    int* cur  = (int*)p;  p += N_NODES * 4;
    int* rowp = (int*)p;  p += (N_NODES + 1) * 4;
    int* csr  = (int*)p;  p += (size_t)TOT_E * 4;

    // ---- CSR build ----
    hipMemsetAsync(deg, 0, sizeof(int) * 2 * N_NODES, stream);  // deg + cur
    int egrid = (TOT_E + 255) / 256;
    deg_k<<<egrid, 256, 0, stream>>>(ei, deg);
    scan_k<<<1, 1024, 0, stream>>>(deg, rowp);
    fill_k<<<egrid, 256, 0, stream>>>(ei, rowp, cur, csr);

    // ---- weight + input conversion (single launch for all weights) ----
    splitx_k<<<(N_NODES * IN_CH + 255) / 256, 256, 0, stream>>>(x, hAhi);
    {
        int tot = SEG0 + 3 * SEGH + SEGO;
        convall_k<<<(tot + 255) / 256, 256, 0, stream>>>(
            W[0], W[1], W[2], W[3], Wh,
            As[0], As[1], As[2], As[3],
            Ad[0], Ad[1], Ad[2], Ad[3],
            wfhi[0], wflo[0], wfhi[1], wflo[1], wfhi[2], wflo[2],
            wfhi[3], wflo[3], whhi, whlo);
    }

    int nmb = (N_NODES + 127) / 128;              // 157
    int gG = nmb * (NT_HID / 6);                  // 471, y-adjacent
    int gO = nmb * (NT_HEAD / 5);                 // 314
    size_t smHid = (size_t)(8192 + 2 * 6 * 512 + 2 * 512) * 2 * 2;         // 61440 B (2 bufs)
    size_t smHead = (size_t)(8192 + 2 * 5 * 512 + 8192 + 2 * 5 * 512) * 2; // 53248 B (1 buf)

    for (int l = 0; l < 4; ++l) {
        int npan = (l == 0) ? PK0 : NP_HID;
        gemm4_k<false, 6, true><<<gG, 256, smHid, stream>>>(hAhi, nullptr, npan,
                                                            wfhi[l], wflo[l], NT_HID, 2,
                                                            hBb, as_, ad_, nullptr, 0, 0, nullptr);
        gat_k<<<N_NODES / 2, 64, 0, stream>>>(hBb, as_, ad_, rowp, csr, Bb[l],
                                              hAhi, (l == 3) ? hAlo : nullptr);
    }

    // head readout (3-term) -> fp32 out [N, 132]
    gemm4_k<true, 5, false><<<gO, 256, smHead, stream>>>(hAhi, hAlo, NP_HEAD,
                                                         whhi, whlo, NT_HEAD, -1,
                                                         nullptr, nullptr, nullptr,
                                                         (float*)d_out, OUTW, OUTW, bh);
}

// Round 12
// 379.159 us; speedup vs baseline: 1.0469x; 1.0003x over previous
//
#include <hip/hip_runtime.h>
#include <hip/hip_bf16.h>

#define N_NODES 20000
#define N_EDGES 320000
#define TOT_E   (N_EDGES + N_NODES)   // 340000 with self loops
#define IN_CH   128
#define HEADS   8
#define CH      33
#define DD      264                   // HEADS*CH
#define OUTW    132
#define NEG     0.2f

#define LDB     272                   // bf16 payload row stride (34 uint4 slots)
#define LDA     320                   // hA bf16 row stride, K padded to 10*32
#define NT_HID  18                    // 17 payload tiles + 1 stats tile [was|wad]
#define NT_HEAD 10                    // head gemm tiles (132 -> 160, zero-padded)
#define PK0     4                     // layer0 K panels (128 exact)
#define PKH     10                    // weight buffer K panels (layout; 9 used)
#define PKO     10
#define NP_HID  9                     // K panels actually processed (264 <= 288)
#define NP_HEAD 9

typedef unsigned short ushort;
typedef unsigned int uint32;
typedef short bf16x8 __attribute__((ext_vector_type(8)));
typedef float f32x4  __attribute__((ext_vector_type(4)));

__device__ inline void split2(float v, ushort& hi, ushort& lo) {
    __hip_bfloat16 h = __float2bfloat16(v);
    float r = v - __bfloat162float(h);
    __hip_bfloat16 l = __float2bfloat16(r);
    hi = *(ushort*)&h;
    lo = *(ushort*)&l;
}

__device__ inline float bf2f(ushort u) {
    union { unsigned int i; float f; } c;
    c.i = ((unsigned int)u) << 16;
    return c.f;
}

// low ushort of dword -> f32 (shift), high ushort -> f32 (free AND)
__device__ inline float bflo(uint32 d) {
    union { unsigned int i; float f; } c;
    c.i = d << 16;
    return c.f;
}
__device__ inline float bfhi(uint32 d) {
    union { unsigned int i; float f; } c;
    c.i = d & 0xffff0000u;
    return c.f;
}

// async global->LDS, 16B per lane; LDS dst is wave-uniform base + lane*16
__device__ __forceinline__ void ld_lds16(const ushort* g, ushort* l) {
    __builtin_amdgcn_global_load_lds(
        (const __attribute__((address_space(1))) void*)g,
        (__attribute__((address_space(3))) void*)l, 16, 0, 0);
}

// ---------------- CSR build (scan + fill; deg fused into prep_k) ----------------

__global__ __launch_bounds__(1024) void scan_k(const int* __restrict__ deg,
                                               int* __restrict__ rowp) {
    __shared__ int part[1024];
    const int PER = 20;
    int t = threadIdx.x;
    int base = t * PER;
    int s = 0;
    for (int i = 0; i < PER; ++i) {
        int idx = base + i;
        if (idx < N_NODES) s += deg[idx];
    }
    part[t] = s;
    __syncthreads();
    for (int off = 1; off < 1024; off <<= 1) {
        int v = 0;
        if (t >= off) v = part[t - off];
        __syncthreads();
        part[t] += v;
        __syncthreads();
    }
    int run = part[t] - s;
    for (int i = 0; i < PER; ++i) {
        int idx = base + i;
        if (idx < N_NODES) { rowp[idx] = run; run += deg[idx]; }
    }
    if (t == 1023) rowp[N_NODES] = part[1023];
}

__global__ void fill_k(const int* __restrict__ ei, const int* __restrict__ rowp,
                       int* __restrict__ cur, int* __restrict__ csr) {
    int e = blockIdx.x * 256 + threadIdx.x;
    if (e >= TOT_E) return;
    int src, dst;
    if (e < N_EDGES) { src = ei[e]; dst = ei[N_EDGES + e]; }
    else             { src = dst = e - N_EDGES; }
    int p = atomicAdd(&cur[dst], 1);
    csr[rowp[dst] + p] = src;
}

// ---------------- fused prep: splitx + deg + all-weight conversion ----------------
// R23: deg_k, splitx_k, convall_k are mutually independent -> one gid-partitioned
// dispatch (saves 2 launch+drain boundaries in the serial prep chain).

__device__ void convw_one(const float* W, const float* a_s, const float* a_d,
                          int K, int NC, int NT, ushort* fhi, ushort* flo, int gid) {
    int p = gid / (NT * 64);
    int rem = gid % (NT * 64);
    int t = rem >> 6, c = rem & 63;
    int kq = c >> 4, m = c & 15;
    int n = t * 16 + m;
    bool stats = (a_s != nullptr) && (t == NT - 1);
    ushort hi8[8], lo8[8];
#pragma unroll
    for (int j = 0; j < 8; ++j) {
        int k = p * 32 + kq * 8 + j;
        float v = 0.f;
        if (k < K) {
            if (stats) {
                const float* av = (m < 8) ? a_s : a_d;
                int h = (m < 8) ? m : m - 8;
                const float* wr = W + (size_t)k * NC + h * CH;
                float s = 0.f;
                for (int cc = 0; cc < CH; ++cc) s += wr[cc] * av[h * CH + cc];
                v = s;
            } else if (n < NC) {
                v = W[(size_t)k * NC + n];
            }
        }
        split2(v, hi8[j], lo8[j]);
    }
    size_t o = ((size_t)gid) * 8;
#pragma unroll
    for (int j = 0; j < 8; ++j) { fhi[o + j] = hi8[j]; flo[o + j] = lo8[j]; }
}

#define SEG0 (PK0 * NT_HID * 64)
#define SEGH (PKH * NT_HID * 64)
#define SEGO (PKO * NT_HEAD * 64)
#define SPLITX_N (N_NODES * IN_CH)

__global__ void prep_k(
    const float* __restrict__ x, ushort* __restrict__ ahi,
    const int* __restrict__ ei, int* __restrict__ deg,
    const float* W0, const float* W1, const float* W2, const float* W3, const float* Wh,
    const float* as0, const float* as1, const float* as2, const float* as3,
    const float* ad0, const float* ad1, const float* ad2, const float* ad3,
    ushort* f0h, ushort* f0l, ushort* f1h, ushort* f1l, ushort* f2h, ushort* f2l,
    ushort* f3h, ushort* f3l, ushort* fhh, ushort* fhl) {
    int gid = blockIdx.x * 256 + threadIdx.x;
    // --- region 1: x -> bf16 (splitx) ---
    if (gid < SPLITX_N) {
        int n = gid >> 7, k = gid & 127;
        __hip_bfloat16 h = __float2bfloat16(x[gid]);
        ahi[(size_t)n * LDA + k] = *(ushort*)&h;
        return;
    }
    gid -= SPLITX_N;
    // --- region 2: degree count ---
    if (gid < TOT_E) {
        int dst = (gid < N_EDGES) ? ei[N_EDGES + gid] : (gid - N_EDGES);
        atomicAdd(&deg[dst], 1);
        return;
    }
    gid -= TOT_E;
    // --- region 3: weight conversion ---
    if (gid < SEG0) { convw_one(W0, as0, ad0, IN_CH, DD, NT_HID, f0h, f0l, gid); return; }
    gid -= SEG0;
    if (gid < SEGH) { convw_one(W1, as1, ad1, DD, DD, NT_HID, f1h, f1l, gid); return; }
    gid -= SEGH;
    if (gid < SEGH) { convw_one(W2, as2, ad2, DD, DD, NT_HID, f2h, f2l, gid); return; }
    gid -= SEGH;
    if (gid < SEGH) { convw_one(W3, as3, ad3, DD, DD, NT_HID, f3h, f3l, gid); return; }
    gid -= SEGH;
    if (gid < SEGO) { convw_one(Wh, nullptr, nullptr, DD, OUTW, NT_HEAD, fhh, fhl, gid); }
}

// ---------------- MFMA GEMM, M=128, BK=64, swizzled A LDS ---------
// R19: global_load_lds width=16 staging; 1D y-adjacent grid.
// R21: 2-phase LDS double-buffer for hidden (DB flag).
// R22: K-trim (264 -> 9 panels); head NT 12->10, TG=5.

template<bool USE3, int TG, bool DB>
__global__ __launch_bounds__(256) void gemm4_k(
    const ushort* __restrict__ Ahi, const ushort* __restrict__ Alo, int npanels,
    const ushort* __restrict__ Bhi, const ushort* __restrict__ Blo, int NTtot, int statsY,
    ushort* __restrict__ Cb16, float* __restrict__ as_, float* __restrict__ ad_,
    float* __restrict__ C, int ldc, int ncguard, const float* __restrict__ bias) {
    extern __shared__ ushort smem[];
    // per-buffer layout: AlH [2][8][512] | BlH [2][TG][512] | EXT
    const int BUFE = 8192 + 2 * TG * 512 + (USE3 ? (8192 + 2 * TG * 512) : 2 * 512);

    int tid = threadIdx.x;
    int ngy = NTtot / TG;
    int m0 = (blockIdx.x / ngy) * 128;
    int by = blockIdx.x % ngy;
    int t0 = by * TG;
    bool sg = (by == statsY);

    f32x4 acc[2][TG];
#pragma unroll
    for (int mt = 0; mt < 2; ++mt)
#pragma unroll
        for (int t = 0; t < TG; ++t) acc[mt][t] = (f32x4){0.f, 0.f, 0.f, 0.f};

    int w = tid >> 6, lane = tid & 63;
    int csA = (lane ^ ((lane >> 4) << 1)) * 8;

    // A-stage source mapping for this lane (slot = lane of each LDS row)
    int kqA = lane >> 4;
    int m15 = (lane ^ (kqA << 1)) & 15;

    // stage panels [kp0, kp0+npan) into buffer slots [0, npan); npan in {1,2}
    auto stage = [&](int kp0, int npan, ushort* base) {
        ushort* AlH_ = base;
        ushort* BlH_ = base + 8192;
        ushort* EXT_ = base + 8192 + 2 * TG * 512;
        ushort* AlL_ = EXT_;
        ushort* BlL_ = EXT_ + 8192;
        ushort* BstL_ = EXT_;
        int pm = npan << 3;                     // A rows per hi/lo half
        int nArows = USE3 ? 2 * pm : pm;
        for (int r = w; r < nArows; r += 4) {
            int hl = (r >= pm) ? 1 : 0;
            int rr = r - hl * pm;
            int panel = rr >> 3;
            int mrow16 = rr & 7;
            int gm = m0 + mrow16 * 16 + m15;
            if (gm > N_NODES - 1) gm = N_NODES - 1;
            const ushort* g = (hl ? Alo : Ahi) + (size_t)gm * LDA + (kp0 + panel) * 32 + kqA * 8;
            ushort* l = (hl ? AlL_ : AlH_) + (panel * 8 + mrow16) * 512;
            ld_lds16(g, l);
        }
        for (int r = w; r < npan * TG; r += 4) {
            int panel = (r >= TG) ? 1 : 0;
            int t = r - panel * TG;
            size_t row = (size_t)((kp0 + panel) * NTtot + t0 + t) * 512;
            ld_lds16(Bhi + row + lane * 8, &BlH_[(panel * TG + t) * 512]);
            if (USE3) ld_lds16(Blo + row + lane * 8, &BlL_[(panel * TG + t) * 512]);
        }
        if (!USE3 && sg && w < npan) {
            int panel = w;
            size_t row = (size_t)((kp0 + panel) * NTtot + t0 + TG - 1) * 512;
            ld_lds16(Blo + row + lane * 8, &BstL_[panel * 512]);
        }
    };

    auto compute = [&](int npan, ushort* base) {
        ushort* AlH_ = base;
        ushort* BlH_ = base + 8192;
        ushort* EXT_ = base + 8192 + 2 * TG * 512;
        ushort* AlL_ = EXT_;
        ushort* BlL_ = EXT_ + 8192;
        ushort* BstL_ = EXT_;
        for (int panel = 0; panel < npan; ++panel) {
            bf16x8 a0 = *(const bf16x8*)&AlH_[panel * 4096 + (2 * w) * 512 + csA];
            bf16x8 a1 = *(const bf16x8*)&AlH_[panel * 4096 + (2 * w + 1) * 512 + csA];
            bf16x8 l0, l1;
            if (USE3) {
                l0 = *(const bf16x8*)&AlL_[panel * 4096 + (2 * w) * 512 + csA];
                l1 = *(const bf16x8*)&AlL_[panel * 4096 + (2 * w + 1) * 512 + csA];
            }
#pragma unroll
            for (int t = 0; t < TG; ++t) {
                bf16x8 bh = *(const bf16x8*)&BlH_[(panel * TG + t) * 512 + lane * 8];
                acc[0][t] = __builtin_amdgcn_mfma_f32_16x16x32_bf16(a0, bh, acc[0][t], 0, 0, 0);
                acc[1][t] = __builtin_amdgcn_mfma_f32_16x16x32_bf16(a1, bh, acc[1][t], 0, 0, 0);
                if (USE3) {
                    bf16x8 bl = *(const bf16x8*)&BlL_[(panel * TG + t) * 512 + lane * 8];
                    acc[0][t] = __builtin_amdgcn_mfma_f32_16x16x32_bf16(a0, bl, acc[0][t], 0, 0, 0);
                    acc[1][t] = __builtin_amdgcn_mfma_f32_16x16x32_bf16(a1, bl, acc[1][t], 0, 0, 0);
                    acc[0][t] = __builtin_amdgcn_mfma_f32_16x16x32_bf16(l0, bh, acc[0][t], 0, 0, 0);
                    acc[1][t] = __builtin_amdgcn_mfma_f32_16x16x32_bf16(l1, bh, acc[1][t], 0, 0, 0);
                } else if (t == TG - 1 && sg) {
                    bf16x8 bst = *(const bf16x8*)&BstL_[panel * 512 + lane * 8];
                    acc[0][t] = __builtin_amdgcn_mfma_f32_16x16x32_bf16(a0, bst, acc[0][t], 0, 0, 0);
                    acc[1][t] = __builtin_amdgcn_mfma_f32_16x16x32_bf16(a1, bst, acc[1][t], 0, 0, 0);
                }
            }
        }
    };

    int npairs = npanels >> 1;
    int nunits = npairs + (npanels & 1);
    auto np_of = [&](int u) { return (u < npairs) ? 2 : 1; };

    if constexpr (DB) {
        stage(0, np_of(0), smem);
        __syncthreads();
        for (int u = 0; u < nunits; ++u) {
            ushort* curb = smem + (u & 1) * BUFE;
            if (u + 1 < nunits) stage(2 * (u + 1), np_of(u + 1), smem + ((u + 1) & 1) * BUFE);
            compute(np_of(u), curb);
            __syncthreads();   // drains vmcnt -> next buffer staged; cur reusable
        }
    } else {
        for (int u = 0; u < nunits; ++u) {
            stage(2 * u, np_of(u), smem);
            __syncthreads();
            compute(np_of(u), smem);
            __syncthreads();
        }
    }

    int col = lane & 15;
#pragma unroll
    for (int mt = 0; mt < 2; ++mt) {
        int rbase = m0 + (2 * w + mt) * 16 + ((lane >> 4) << 2);
#pragma unroll
        for (int t = 0; t < TG; ++t) {
            int tg = t0 + t;
#pragma unroll
            for (int r = 0; r < 4; ++r) {
                int gm = rbase + r;
                if (gm >= N_NODES) continue;
                float v = acc[mt][t][r];
                if (C) {
                    int gn = tg * 16 + col;
                    if (gn < ncguard) C[(size_t)gm * ldc + gn] = v + bias[gn];
                } else if (tg < 17) {
                    __hip_bfloat16 bv = __float2bfloat16(v);
                    Cb16[(size_t)gm * LDB + tg * 16 + col] = *(ushort*)&bv;
                } else {
                    if (col < 8) as_[(size_t)gm * 8 + col] = v;
                    else         ad_[(size_t)gm * 8 + col - 8] = v;
                }
            }
        }
    }
}

// ---------------- fused softmax + gather-aggregate: 2 nodes / wave (R18) ----------

__global__ __launch_bounds__(64) void gat_k(
    const ushort* __restrict__ xb, const float* __restrict__ as_,
    const float* __restrict__ ad_, const int* __restrict__ rowp,
    const int* __restrict__ csr, const float* __restrict__ bias,
    ushort* __restrict__ outhi, ushort* __restrict__ outlo) {
    int lane = threadIdx.x;
    int half = lane >> 5, l32 = lane & 31;
    int node = blockIdx.x * 2 + half;       // grid is exactly N/2
    int r0 = rowp[node], dg = rowp[node + 1] - r0;

    __shared__ float lex[2][32][9];
    __shared__ int   lsrc[2][32];

    float ad[8];
#pragma unroll
    for (int h = 0; h < 8; ++h) ad[h] = ad_[node * 8 + h];

    // this lane's 8 channels: cb..cb+7; they span at most 2 heads
    int cb = l32 * 8;
    int ha = cb / 33;
    int hb = (cb + 7) / 33;
    bool mm[8];
#pragma unroll
    for (int j = 0; j < 8; ++j) mm[j] = ((cb + j) / 33) != ha;

    float a0[8];
#pragma unroll
    for (int j = 0; j < 8; ++j) a0[j] = 0.f;
    float a1[4] = {0.f, 0.f, 0.f, 0.f};   // tail: even l32 ch 256-259, odd 260-263
    float sm[8] = {0.f, 0.f, 0.f, 0.f, 0.f, 0.f, 0.f, 0.f};

    int mych = (dg + 31) >> 5;
    int och = __shfl_xor(mych, 32, 64);
    int maxch = mych > och ? mych : och;

    for (int c = 0; c < maxch; ++c) {
        int base = c << 5, j = base + l32;
        int s = node;
        float p8[8];
#pragma unroll
        for (int h = 0; h < 8; ++h) p8[h] = 0.f;
        if (j < dg) {
            s = csr[r0 + j];
            const float* ap = as_ + (size_t)s * 8;
#pragma unroll
            for (int h = 0; h < 8; ++h) {
                float e = ap[h] + ad[h];
                e = e > 0.f ? e : NEG * e;
                float p = __expf(e);
                p8[h] = p;
                sm[h] += p;
            }
        }
        lsrc[half][l32] = s * LDB;   // pre-scaled row offset (ushorts)
#pragma unroll
        for (int h = 0; h < 8; ++h) lex[half][l32][h] = p8[h];
        __builtin_amdgcn_wave_barrier();

        int rem = dg - base;
        int cnt = rem < 0 ? 0 : (rem > 32 ? 32 : rem);
        int cnt4 = (cnt + 3) & ~3;
        for (int jj = 0; jj < cnt4; jj += 4) {
            int o0 = lsrc[half][jj + 0], o1 = lsrc[half][jj + 1];
            int o2 = lsrc[half][jj + 2], o3 = lsrc[half][jj + 3];
            const uint4* p0 = (const uint4*)(xb + (size_t)(unsigned)o0);
            const uint4* p1 = (const uint4*)(xb + (size_t)(unsigned)o1);
            const uint4* p2 = (const uint4*)(xb + (size_t)(unsigned)o2);
            const uint4* p3 = (const uint4*)(xb + (size_t)(unsigned)o3);
            uint4 v0 = p0[l32], v1 = p1[l32], v2 = p2[l32], v3 = p3[l32];
            // tail: uint2 slots 64/65 (ch 256-263), parity-split broadcast
            const uint2* q0 = (const uint2*)p0;
            const uint2* q1 = (const uint2*)p1;
            const uint2* q2 = (const uint2*)p2;
            const uint2* q3 = (const uint2*)p3;
            uint2 t0 = q0[64 + (l32 & 1)], t1 = q1[64 + (l32 & 1)];
            uint2 t2 = q2[64 + (l32 & 1)], t3 = q3[64 + (l32 & 1)];
#pragma unroll
            for (int e = 0; e < 4; ++e) {
                const float* xr = lex[half][jj + e];
                float xa = xr[ha], xbv = xr[hb], x7 = xr[7];
                uint4 v = (e == 0) ? v0 : (e == 1) ? v1 : (e == 2) ? v2 : v3;
                uint2 t = (e == 0) ? t0 : (e == 1) ? t1 : (e == 2) ? t2 : t3;
                a0[0] += (mm[0] ? xbv : xa) * bflo(v.x);
                a0[1] += (mm[1] ? xbv : xa) * bfhi(v.x);
                a0[2] += (mm[2] ? xbv : xa) * bflo(v.y);
                a0[3] += (mm[3] ? xbv : xa) * bfhi(v.y);
                a0[4] += (mm[4] ? xbv : xa) * bflo(v.z);
                a0[5] += (mm[5] ? xbv : xa) * bfhi(v.z);
                a0[6] += (mm[6] ? xbv : xa) * bflo(v.w);
                a0[7] += (mm[7] ? xbv : xa) * bfhi(v.w);
                a1[0] += x7 * bflo(t.x);
                a1[1] += x7 * bfhi(t.x);
                a1[2] += x7 * bflo(t.y);
                a1[3] += x7 * bfhi(t.y);
            }
        }
        __builtin_amdgcn_wave_barrier();
    }

    // deferred sum reduction -> iv[8]; xor offsets <=16 stay within each half
    float iv[8];
#pragma unroll
    for (int h = 0; h < 8; ++h) {
        float s = sm[h];
        for (int off = 16; off; off >>= 1) s += __shfl_xor(s, off, 64);
        iv[h] = 1.0f / (s + 1e-16f);
    }

    // epilogue: normalize, bias + elu, bf16 out (hi; lo when requested)
    {
        float iva = iv[ha], ivb = iv[hb];
        ushort hi8[8], lo8[8];
        float4 b0 = *(const float4*)(bias + cb);
        float4 b1 = *(const float4*)(bias + cb + 4);
        float bv4[8] = {b0.x, b0.y, b0.z, b0.w, b1.x, b1.y, b1.z, b1.w};
#pragma unroll
        for (int j = 0; j < 8; ++j) {
            float v = a0[j] * (mm[j] ? ivb : iva) + bv4[j];
            v = v > 0.f ? v : (__expf(v) - 1.f);
            split2(v, hi8[j], lo8[j]);
        }
        size_t o = (size_t)node * LDA + cb;
        *(ushort4*)(outhi + o) = *(ushort4*)&hi8[0];
        *(ushort4*)(outhi + o + 4) = *(ushort4*)&hi8[4];
        if (outlo) {
            *(ushort4*)(outlo + o) = *(ushort4*)&lo8[0];
            *(ushort4*)(outlo + o + 4) = *(ushort4*)&lo8[4];
        }
    }
    if (l32 < 2) {
        ushort hi4[4], lo4[4];
        float4 bt = *(const float4*)(bias + 256 + l32 * 4);
        float bv4[4] = {bt.x, bt.y, bt.z, bt.w};
#pragma unroll
        for (int j = 0; j < 4; ++j) {
            float v = a1[j] * iv[7] + bv4[j];
            v = v > 0.f ? v : (__expf(v) - 1.f);
            split2(v, hi4[j], lo4[j]);
        }
        size_t o = (size_t)node * LDA + 256 + l32 * 4;
        *(ushort4*)(outhi + o) = *(ushort4*)hi4;
        if (outlo) *(ushort4*)(outlo + o) = *(ushort4*)lo4;
    } else if (l32 < 9) {
        ushort4 z = {0, 0, 0, 0};
        size_t o = (size_t)node * LDA + 264 + (l32 - 2) * 8;
        *(ushort4*)(outhi + o) = z;
        *(ushort4*)(outhi + o + 4) = z;
        if (outlo) {
            *(ushort4*)(outlo + o) = z;
            *(ushort4*)(outlo + o + 4) = z;
        }
    }
}

// ---------------- launch ----------------

extern "C" void kernel_launch(void* const* d_in, const int* in_sizes, int n_in,
                              void* d_out, int out_size, void* d_ws, size_t ws_size,
                              hipStream_t stream) {
    const float* x  = (const float*)d_in[0];
    const int*   ei = (const int*)d_in[1];
    const float* W[4]  = {(const float*)d_in[2],  (const float*)d_in[6],
                          (const float*)d_in[10], (const float*)d_in[14]};
    const float* As[4] = {(const float*)d_in[3],  (const float*)d_in[7],
                          (const float*)d_in[11], (const float*)d_in[15]};
    const float* Ad[4] = {(const float*)d_in[4],  (const float*)d_in[8],
                          (const float*)d_in[12], (const float*)d_in[16]};
    const float* Bb[4] = {(const float*)d_in[5],  (const float*)d_in[9],
                          (const float*)d_in[13], (const float*)d_in[17]};
    const float* Wh = (const float*)d_in[18];
    const float* bh = (const float*)d_in[19];

    // ---- workspace carve ----
    char* p = (char*)d_ws;
    ushort* hBb  = (ushort*)p;          p += (size_t)N_NODES * LDB * 2;
    ushort* hAhi = (ushort*)p;          p += (size_t)N_NODES * LDA * 2;
    ushort* hAlo = (ushort*)p;          p += (size_t)N_NODES * LDA * 2;
    float* as_  = (float*)p;            p += (size_t)N_NODES * HEADS * 4;
    float* ad_  = (float*)p;            p += (size_t)N_NODES * HEADS * 4;
    const int wsz0 = PK0 * NT_HID * 512;
    const int wszH = PKH * NT_HID * 512;
    const int wszO = PKO * NT_HEAD * 512;
    ushort* wfhi[4]; ushort* wflo[4];
    for (int l = 0; l < 4; ++l) {
        int sz = (l == 0) ? wsz0 : wszH;
        wfhi[l] = (ushort*)p; p += (size_t)sz * 2;
        wflo[l] = (ushort*)p; p += (size_t)sz * 2;
    }
    ushort* whhi = (ushort*)p; p += (size_t)wszO * 2;
    ushort* whlo = (ushort*)p; p += (size_t)wszO * 2;
    int* deg  = (int*)p;  p += N_NODES * 4;
    int* cur  = (int*)p;  p += N_NODES * 4;
    int* rowp = (int*)p;  p += (N_NODES + 1) * 4;
    int* csr  = (int*)p;  p += (size_t)TOT_E * 4;

    // ---- fused prep: memset -> prep_k (splitx + deg + convall) -> scan -> fill ----
    hipMemsetAsync(deg, 0, sizeof(int) * 2 * N_NODES, stream);  // deg + cur
    {
        int tot = SPLITX_N + TOT_E + SEG0 + 3 * SEGH + SEGO;
        prep_k<<<(tot + 255) / 256, 256, 0, stream>>>(
            x, hAhi, ei, deg,
            W[0], W[1], W[2], W[3], Wh,
            As[0], As[1], As[2], As[3],
            Ad[0], Ad[1], Ad[2], Ad[3],
            wfhi[0], wflo[0], wfhi[1], wflo[1], wfhi[2], wflo[2],
            wfhi[3], wflo[3], whhi, whlo);
    }
    scan_k<<<1, 1024, 0, stream>>>(deg, rowp);
    int egrid = (TOT_E + 255) / 256;
    fill_k<<<egrid, 256, 0, stream>>>(ei, rowp, cur, csr);

    int nmb = (N_NODES + 127) / 128;              // 157
    int gG = nmb * (NT_HID / 6);                  // 471, y-adjacent
    int gO = nmb * (NT_HEAD / 5);                 // 314
    size_t smHid = (size_t)(8192 + 2 * 6 * 512 + 2 * 512) * 2 * 2;         // 61440 B (2 bufs)
    size_t smHead = (size_t)(8192 + 2 * 5 * 512 + 8192 + 2 * 5 * 512) * 2; // 53248 B (1 buf)

    for (int l = 0; l < 4; ++l) {
        int npan = (l == 0) ? PK0 : NP_HID;
        gemm4_k<false, 6, true><<<gG, 256, smHid, stream>>>(hAhi, nullptr, npan,
                                                            wfhi[l], wflo[l], NT_HID, 2,
                                                            hBb, as_, ad_, nullptr, 0, 0, nullptr);
        gat_k<<<N_NODES / 2, 64, 0, stream>>>(hBb, as_, ad_, rowp, csr, Bb[l],
                                              hAhi, (l == 3) ? hAlo : nullptr);
    }

    // head readout (3-term) -> fp32 out [N, 132]
    gemm4_k<true, 5, false><<<gO, 256, smHead, stream>>>(hAhi, hAlo, NP_HEAD,
                                                         whhi, whlo, NT_HEAD, -1,
                                                         nullptr, nullptr, nullptr,
                                                         (float*)d_out, OUTW, OUTW, bh);
}